// Round 3
// baseline (888.784 us; speedup 1.0000x reference)
//
#include <hip/hip_runtime.h>
#include <hip/hip_bf16.h>
#include <stdint.h>

#define DEV __device__ __forceinline__

typedef __bf16 bf16x8 __attribute__((ext_vector_type(8)));
typedef float f32x4 __attribute__((ext_vector_type(4)));
typedef unsigned short us8 __attribute__((ext_vector_type(8)));
typedef int8_t i8x8 __attribute__((ext_vector_type(8)));

DEV unsigned short f2us(float f) {
  __hip_bfloat16 h = __float2bfloat16(f);
  unsigned short u;
  __builtin_memcpy(&u, &h, 2);
  return u;
}

DEV double wave_reduce_d(double v) {
#pragma unroll
  for (int off = 32; off > 0; off >>= 1) v += __shfl_down(v, off);
  return v;
}

DEV double dbl_block_reduce(double v, double* lds) {
  v = wave_reduce_d(v);
  int lane = threadIdx.x & 63, w = threadIdx.x >> 6;
  if (lane == 0) lds[w] = v;
  __syncthreads();
  double r = 0.0;
  if (threadIdx.x == 0) r = lds[0] + lds[1] + lds[2] + lds[3];
  __syncthreads();
  return r;
}

// ---------------- ternarize: fp64 stats, flat proportional grid ----------------
struct TDesc { const float* w; int n; int b0; int nb; int slot; };
struct TDescs { TDesc d[6]; };

DEV double abs4d(float4 v) {
  return fabs((double)v.x) + fabs((double)v.y) + fabs((double)v.z) + fabs((double)v.w);
}

DEV double bucket_sum64(const double* b) {
  double s = 0.0;
#pragma unroll
  for (int j = 0; j < 64; ++j) s += b[j];
  return s;
}

// one launch, all 6 tensors: sum|w| into absB[slot*64 + (blk&63)].
__global__ __launch_bounds__(256) void tern_abs_all(TDescs td, double* __restrict__ absB) {
  __shared__ double lds[4];
  const int b = blockIdx.x;
  int k = 0;
  while (k < 5 && b >= td.d[k + 1].b0) ++k;  // d[] sorted ascending by b0
  const TDesc D = td.d[k];
  const float4* w4 = (const float4*)D.w;
  const int n4 = D.n >> 2;
  const int S = D.nb * 256;
  int i = (b - D.b0) * 256 + threadIdx.x;
  double s0 = 0.0, s1 = 0.0, s2 = 0.0, s3 = 0.0;
  for (; i + 3 * S < n4; i += 4 * S) {
    float4 v0 = w4[i];
    float4 v1 = w4[i + S];
    float4 v2 = w4[i + 2 * S];
    float4 v3 = w4[i + 3 * S];
    s0 += abs4d(v0);
    s1 += abs4d(v1);
    s2 += abs4d(v2);
    s3 += abs4d(v3);
  }
  for (; i < n4; i += S) s0 += abs4d(w4[i]);
  double s = (s0 + s1) + (s2 + s3);
  s = dbl_block_reduce(s, lds);
  if (threadIdx.x == 0 && s != 0.0) atomicAdd(absB + D.slot * 64 + (b & 63), s);
}

struct MDesc { const float* w; int8_t* out; int n; int b0; int nb; int slot; };
struct MDescs { MDesc d[6]; };

DEV int proc4(float4 v, double delta, double& ms, int& cnt) {
  float e[4] = {v.x, v.y, v.z, v.w};
  char pk[4];
#pragma unroll
  for (int j = 0; j < 4; ++j) {
    double d = (double)e[j];
    double a = fabs(d);
    if (a > delta) { ms += a; cnt += 1; }
    pk[j] = (char)((d > delta) ? 1 : ((d < -delta) ? -1 : 0));
  }
  int w32;
  __builtin_memcpy(&w32, pk, 4);
  return w32;
}

__global__ __launch_bounds__(256) void tern_masked_code_all(MDescs td,
                                                            const double* __restrict__ absB,
                                                            double* __restrict__ msB,
                                                            double* __restrict__ cntB) {
  __shared__ double lds[4];
  const int b = blockIdx.x;
  int k = 0;
  while (k < 5 && b >= td.d[k + 1].b0) ++k;
  const MDesc D = td.d[k];
  const float4* w4 = (const float4*)D.w;
  int8_t* out = D.out;
  const int n4 = D.n >> 2;
  const double delta = 0.7 * bucket_sum64(absB + D.slot * 64) / (double)D.n;
  const int S = D.nb * 256;
  int i = (b - D.b0) * 256 + threadIdx.x;
  double m0 = 0.0, m1 = 0.0, m2 = 0.0, m3 = 0.0;
  int c0 = 0, c1x = 0, c2x = 0, c3 = 0;
  for (; i + 3 * S < n4; i += 4 * S) {
    float4 v0 = w4[i];
    float4 v1 = w4[i + S];
    float4 v2 = w4[i + 2 * S];
    float4 v3 = w4[i + 3 * S];
    int p0 = proc4(v0, delta, m0, c0);
    int p1 = proc4(v1, delta, m1, c1x);
    int p2 = proc4(v2, delta, m2, c2x);
    int p3 = proc4(v3, delta, m3, c3);
    if (out) {
      *(int*)(out + ((size_t)i << 2)) = p0;
      *(int*)(out + ((size_t)(i + S) << 2)) = p1;
      *(int*)(out + ((size_t)(i + 2 * S) << 2)) = p2;
      *(int*)(out + ((size_t)(i + 3 * S) << 2)) = p3;
    }
  }
  for (; i < n4; i += S) {
    int p = proc4(w4[i], delta, m0, c0);
    if (out) *(int*)(out + ((size_t)i << 2)) = p;
  }
  double ms = (m0 + m1) + (m2 + m3);
  double cnt = (double)(c0 + c1x + c2x + c3);
  ms = dbl_block_reduce(ms, lds);
  cnt = dbl_block_reduce(cnt, lds);
  if (threadIdx.x == 0 && cnt != 0.0) {
    atomicAdd(msB + D.slot * 64 + (b & 63), ms);
    atomicAdd(cntB + D.slot * 64 + (b & 63), cnt);
  }
}

// collapse 64 buckets -> st[t*4 + {0,1,2}] for downstream consumers
__global__ __launch_bounds__(64) void tern_collapse(const double* __restrict__ absB,
                                                    const double* __restrict__ msB,
                                                    const double* __restrict__ cntB,
                                                    double* __restrict__ st) {
  const int t = blockIdx.x;
  const int lane = threadIdx.x;
  double a = absB[t * 64 + lane];
  double m = msB[t * 64 + lane];
  double c = cntB[t * 64 + lane];
#pragma unroll
  for (int off = 32; off > 0; off >>= 1) {
    a += __shfl_down(a, off);
    m += __shfl_down(m, off);
    c += __shfl_down(c, off);
  }
  if (lane == 0) {
    st[t * 4] = a;
    st[t * 4 + 1] = m;
    st[t * 4 + 2] = c;
  }
}

DEV float tern_alpha_d(const double* st, double n) {
  double cnt = st[2];
  return (float)(cnt > 0.0 ? st[1] / fmax(cnt, 1.0) : st[0] / n);
}
DEV double tern_alpha_dd(const double* st, double n) {
  double cnt = st[2];
  return cnt > 0.0 ? st[1] / fmax(cnt, 1.0) : st[0] / n;
}

// conv2-4 weights -> bf16 codes {-1,0,+1}, layout [cout][k=tap*CIN+ci]
__global__ __launch_bounds__(256) void tern_write_convb(const float* __restrict__ w,
                                                        const double* __restrict__ ab, int total,
                                                        int CIN, unsigned short* __restrict__ out) {
  int i = blockIdx.x * 256 + threadIdx.x;
  if (i >= total) return;
  double delta = 0.7 * bucket_sum64(ab) / (double)total;
  double v = (double)w[i];
  float code = v > delta ? 1.f : (v < -delta ? -1.f : 0.f);
  int cin9 = CIN * 9;
  int o = i / cin9, rem = i - o * cin9;
  int ci = rem / 9, tap = rem - ci * 9;
  out[(size_t)o * cin9 + tap * CIN + ci] = f2us(code);
}

// conv1 weights (cin=3) -> bf16 codes padded to 32 ci: [64][k=tap*32+ci]
__global__ __launch_bounds__(256) void tern_write_convb_pad(const float* __restrict__ w,
                                                            const double* __restrict__ ab,
                                                            unsigned short* __restrict__ out) {
  int i = blockIdx.x * 256 + threadIdx.x;
  if (i >= 64 * 288) return;
  int o = i / 288, rem = i - o * 288;
  int tap = rem >> 5, ci = rem & 31;
  float code = 0.f;
  if (ci < 3) {
    double delta = 0.7 * bucket_sum64(ab) / 1728.0;
    double v = (double)w[(o * 3 + ci) * 9 + tap];
    code = v > delta ? 1.f : (v < -delta ? -1.f : 0.f);
  }
  out[i] = f2us(code);
}

// ---------------- BN finalize (alpha-folded; bias cancels exactly) ----------------
// pS/pQ layout is [p][co] (coalesced writes from conv; strided-but-L2-hit reads here)
__global__ __launch_bounds__(256) void bn_fin_alpha(const double* __restrict__ pS,
                                                    const double* __restrict__ pQ, int P,
                                                    const float* __restrict__ g,
                                                    const float* __restrict__ be, double M,
                                                    const double* __restrict__ st, double nels,
                                                    float* __restrict__ scsh, int C) {
  __shared__ double lds[4];
  const int c = blockIdx.x;
  double s = 0.0, q = 0.0;
  for (int p = threadIdx.x; p < P; p += 256) {
    s += pS[(size_t)p * C + c];
    q += pQ[(size_t)p * C + c];
  }
  s = dbl_block_reduce(s, lds);
  q = dbl_block_reduce(q, lds);
  if (threadIdx.x == 0) {
    double al = tern_alpha_dd(st, nels);
    double mean = s / M;
    double var = q / M - mean * mean;
    double sc = (double)g[c] * al / sqrt(al * al * var + 1e-5);
    scsh[c] = (float)sc;
    scsh[C + c] = (float)((double)be[c] - mean * sc);
  }
}

// ---------------- x NCHW(3ch) -> NHWC padded to 32ch fp32 ----------------
__global__ __launch_bounds__(256) void pad32(const float* __restrict__ x,
                                             float* __restrict__ x32) {
  int i = blockIdx.x * 256 + threadIdx.x;  // 32*16384
  int px = i & 16383, n = i >> 14;
  float v0 = x[((size_t)n * 3 + 0) * 16384 + px];
  float v1 = x[((size_t)n * 3 + 1) * 16384 + px];
  float v2 = x[((size_t)n * 3 + 2) * 16384 + px];
  float4* dst = (float4*)(x32 + (size_t)i * 32);
  dst[0] = make_float4(v0, v1, v2, 0.f);
  float4 z = make_float4(0.f, 0.f, 0.f, 0.f);
#pragma unroll
  for (int j = 1; j < 8; ++j) dst[j] = z;
}

// ---------------- NCHW fp32 -> NHWC fp32 transpose ----------------
__global__ __launch_bounds__(256) void nchw2nhwc(const float* __restrict__ in,
                                                 float* __restrict__ out, int C, int HW) {
  __shared__ float t[64][65];
  const int c0 = blockIdx.x * 64, p0 = blockIdx.y * 64, n = blockIdx.z;
  const float* src = in + (size_t)n * C * HW;
  for (int u = threadIdx.x; u < 4096; u += 256) {
    int cl = u >> 6, pl = u & 63;
    t[cl][pl] = src[(size_t)(c0 + cl) * HW + p0 + pl];
  }
  __syncthreads();
  float* dst = out + (size_t)n * HW * C;
  for (int u = threadIdx.x; u < 4096; u += 256) {
    int pl = u >> 6, cl = u & 63;
    dst[(size_t)(p0 + pl) * C + c0 + cl] = t[cl][pl];
  }
}

// ---------------- hi/lo bf16 split helper ----------------
DEV void cvt8(float4 a, float4 b, us8& hv, us8& lv) {
  float f[8] = {a.x, a.y, a.z, a.w, b.x, b.y, b.z, b.w};
#pragma unroll
  for (int e = 0; e < 8; ++e) {
    __hip_bfloat16 h = __float2bfloat16(f[e]);
    unsigned short hu;
    __builtin_memcpy(&hu, &h, 2);
    hv[e] = hu;
    lv[e] = f2us(f[e] - __bfloat162float(h));
  }
}

// fused fp64 BN partial write (per wave, 16-lane reduce), layout [p][co]
template <int PH>
DEV void bn_partials(const f32x4 (&acc)[2][PH], int wvCout, int CO, int p,
                     double* __restrict__ pS, double* __restrict__ pQ) {
  const int lane = threadIdx.x & 63;
  const int l15 = lane & 15, l4 = lane >> 4;
#pragma unroll
  for (int g = 0; g < 2; ++g) {
    float sv[4] = {0, 0, 0, 0}, qv[4] = {0, 0, 0, 0};
#pragma unroll
    for (int pt = 0; pt < PH; ++pt)
#pragma unroll
      for (int r = 0; r < 4; ++r) {
        float v = acc[g][pt][r];
        sv[r] += v;
        qv[r] = fmaf(v, v, qv[r]);
      }
#pragma unroll
    for (int r = 0; r < 4; ++r)
#pragma unroll
      for (int m = 1; m < 16; m <<= 1) {
        sv[r] += __shfl_xor(sv[r], m);
        qv[r] += __shfl_xor(qv[r], m);
      }
    if (l15 == 0) {
#pragma unroll
      for (int r = 0; r < 4; ++r) {
        int co = wvCout + g * 16 + l4 * 4 + r;
        pS[(size_t)p * CO + co] = (double)sv[r];
        pQ[(size_t)p * CO + co] = (double)qv[r];
      }
    }
  }
}

// ---------------- layers 2-4: 8-wave split-K conv (PH=2, padded LDS) ----------------
// Waves 0-3 process K-chunks [0,CH/2), waves 4-7 process [CH/2,CH) on the SAME
// spatial/cout tile (weight L2 traffic unchanged, resident waves doubled ->
// 8192 waves = 100% of slots; old 4-wave scheme capped at 50%).
// LDS row stride padded 32->40 shorts: bank base cycles 8 values, killing the
// 8-way ds_read_b128 conflict of the 64B stride.  fp32 cross-group combine via
// LDS at the end; group-0 waves do z-write + BN partials.
template <int CIN, int H>
__global__ __launch_bounds__(512, 8) void conv_ks(const float* __restrict__ inNHWC,
                                                  const unsigned short* __restrict__ wT,
                                                  float* __restrict__ z, int COUT,
                                                  double* __restrict__ pS,
                                                  double* __restrict__ pQ) {
  constexpr int PH = 2;
  constexpr int W = H;
  constexpr int CH = CIN / 32;
  constexpr int CH2 = CH / 2;
  constexpr int K = 9 * CIN;
  constexpr int TX = W / 16;
  constexpr int ROWS = (PH + 2) * 18;  // 72 tile rows (y-halo x x-halo)
  constexpr int RP = 40;               // padded row stride in shorts
  constexpr int TILE = ROWS * RP;      // 2880 shorts
  constexpr int NU2 = ROWS * 2;        // 144 16-float staging units per tile
  __shared__ __align__(16) unsigned short sbuf[4 * TILE];  // hi[2] | lo[2] : 23040 B
  unsigned short* hiB = sbuf;
  unsigned short* loB = sbuf + 2 * TILE;

  const int bx = blockIdx.x;
  const int tX = bx % TX, tY = bx / TX;
  const int n = blockIdx.z;
  const int wave = threadIdx.x >> 6, lane = threadIdx.x & 63;
  const int kg = wave >> 2;
  const int l15 = lane & 15, l4 = lane >> 4;
  const int wvCout = blockIdx.y * 128 + (wave & 3) * 32;
  const int x0 = tX * 16, y0 = tY * PH;

  f32x4 acc[2][PH];
#pragma unroll
  for (int g = 0; g < 2; ++g)
#pragma unroll
    for (int pt = 0; pt < PH; ++pt) acc[g][pt] = (f32x4){0.f, 0.f, 0.f, 0.f};

  // one 16-float (32ci-half) staging unit per thread; 288 of 512 threads active
  const int u = threadIdx.x;
  const bool act = u < 2 * NU2;
  const int ug = (u >= NU2) ? 1 : 0;
  const int v = u - ug * NU2;
  const int q2 = v & 1, rem = v >> 1;
  const int xx = rem % 18, yy = rem / 18;
  const int gy = y0 + yy - 1, gx = x0 + xx - 1;
  const bool inb = act && (unsigned)gy < (unsigned)H && (unsigned)gx < (unsigned)W;
  const int cy = inb ? gy : 0, cx = inb ? gx : 0;
  const int srcO = ((n * H + cy) * W + cx) * CIN + ug * (CH2 * 32) + q2 * 16;
  const int dstO = ug * TILE + rem * RP + q2 * 16;

  float4 pa, pb, pc, pd;
  if (inb) {
    const float* s0 = inNHWC + srcO;
    pa = *(const float4*)s0;
    pb = *(const float4*)(s0 + 4);
    pc = *(const float4*)(s0 + 8);
    pd = *(const float4*)(s0 + 12);
  }

#pragma unroll 1
  for (int p = 0; p < CH2; ++p) {
    if (act) {
      us8 h0 = (us8)0, l0 = (us8)0, h1 = (us8)0, l1 = (us8)0;
      if (inb) {
        cvt8(pa, pb, h0, l0);
        cvt8(pc, pd, h1, l1);
      }
      *(us8*)(hiB + dstO) = h0;
      *(us8*)(hiB + dstO + 8) = h1;
      *(us8*)(loB + dstO) = l0;
      *(us8*)(loB + dstO + 8) = l1;
    }
    asm volatile("s_waitcnt lgkmcnt(0)" ::: "memory");
    __builtin_amdgcn_s_barrier();
    __builtin_amdgcn_sched_barrier(0);
    // prefetch next chunk's globals; they fly under the MFMA phase (T14)
    if (p + 1 < CH2 && inb) {
      const float* s1 = inNHWC + srcO + (p + 1) * 32;
      pa = *(const float4*)s1;
      pb = *(const float4*)(s1 + 4);
      pc = *(const float4*)(s1 + 8);
      pd = *(const float4*)(s1 + 12);
    }
    const int c = kg * CH2 + p;
    const unsigned short* hT = hiB + kg * TILE;
    const unsigned short* lT = loB + kg * TILE;
#pragma unroll
    for (int tap = 0; tap < 9; ++tap) {
      const int dy = tap / 3, dx = tap % 3;
      bf16x8 aF[2];
#pragma unroll
      for (int g = 0; g < 2; ++g) {
        int co = wvCout + g * 16 + l15;
        aF[g] = *(const bf16x8*)(wT + (size_t)co * K + tap * CIN + c * 32 + l4 * 8);
      }
      const int tb = (dy * 18 + dx + l15) * RP + l4 * 8;
#pragma unroll
      for (int pt = 0; pt < PH; ++pt) {
        int off = tb + pt * (18 * RP);
        bf16x8 bh = *(const bf16x8*)(hT + off);
        bf16x8 bl = *(const bf16x8*)(lT + off);
        acc[0][pt] = __builtin_amdgcn_mfma_f32_16x16x32_bf16(aF[0], bh, acc[0][pt], 0, 0, 0);
        acc[1][pt] = __builtin_amdgcn_mfma_f32_16x16x32_bf16(aF[1], bh, acc[1][pt], 0, 0, 0);
        acc[0][pt] = __builtin_amdgcn_mfma_f32_16x16x32_bf16(aF[0], bl, acc[0][pt], 0, 0, 0);
        acc[1][pt] = __builtin_amdgcn_mfma_f32_16x16x32_bf16(aF[1], bl, acc[1][pt], 0, 0, 0);
      }
    }
    __builtin_amdgcn_s_barrier();
    __builtin_amdgcn_sched_barrier(0);
  }

  // cross-group combine: kg1 accs -> LDS -> kg0 adds; kg0 does the epilogue
  float* ldsV = (float*)sbuf;  // 16 KB needed; sbuf is 23 KB
  if (kg == 1) {
    int t = threadIdx.x & 255;
#pragma unroll
    for (int g = 0; g < 2; ++g)
#pragma unroll
      for (int pt = 0; pt < PH; ++pt)
        *(f32x4*)(ldsV + (size_t)((g * PH + pt) * 256 + t) * 4) = acc[g][pt];
  }
  asm volatile("s_waitcnt lgkmcnt(0)" ::: "memory");
  __builtin_amdgcn_s_barrier();
  __builtin_amdgcn_sched_barrier(0);
  if (kg == 0) {
    int t = threadIdx.x;
#pragma unroll
    for (int g = 0; g < 2; ++g)
#pragma unroll
      for (int pt = 0; pt < PH; ++pt)
        acc[g][pt] += *(const f32x4*)(ldsV + (size_t)((g * PH + pt) * 256 + t) * 4);
#pragma unroll
    for (int g = 0; g < 2; ++g)
#pragma unroll
      for (int pt = 0; pt < PH; ++pt) {
        int oy = y0 + pt;
#pragma unroll
        for (int r = 0; r < 4; ++r) {
          int co = wvCout + g * 16 + l4 * 4 + r;
          z[(((size_t)n * COUT + co) * H + oy) * W + x0 + l15] = acc[g][pt][r];
        }
      }
    bn_partials<PH>(acc, wvCout, COUT, n * gridDim.x + bx, pS, pQ);
  }
}

// ---------------- conv1 body (CH==1, unpadded 32-short rows) ----------------
template <int PH, int NW>
DEV void conv1_body(const float* __restrict__ inNHWC, const unsigned short* __restrict__ wT,
                    int wvCout, int n, int x0, int y0, unsigned short* hiT, unsigned short* loT,
                    f32x4 (&acc)[2][PH]) {
  constexpr int H = 128, W = 128, CIN = 32, K = 288;
  constexpr int NU = (PH + 2) * 18 * 4;
  constexpr int T = NW * 64;
  const int lane = threadIdx.x & 63;
  const int l15 = lane & 15, l4 = lane >> 4;

#pragma unroll
  for (int g = 0; g < 2; ++g)
#pragma unroll
    for (int pt = 0; pt < PH; ++pt) acc[g][pt] = (f32x4){0.f, 0.f, 0.f, 0.f};

  for (int u = threadIdx.x; u < NU; u += T) {
    int q = u & 3, rem = u >> 2;
    int xx = rem % 18, yy = rem / 18;
    int gy = y0 + yy - 1, gx = x0 + xx - 1;
    us8 hv = (us8)0, lv = (us8)0;
    if ((unsigned)gy < (unsigned)H && (unsigned)gx < (unsigned)W) {
      const float* src = inNHWC + (((size_t)(n * H + gy) * W + gx) * CIN + q * 8);
      cvt8(*(const float4*)src, *(const float4*)(src + 4), hv, lv);
    }
    int off = (rem << 5) + (q << 3);
    *(us8*)(hiT + off) = hv;
    *(us8*)(loT + off) = lv;
  }
  asm volatile("s_waitcnt lgkmcnt(0)" ::: "memory");
  __builtin_amdgcn_s_barrier();
  __builtin_amdgcn_sched_barrier(0);
#pragma unroll
  for (int tap = 0; tap < 9; ++tap) {
    const int dy = tap / 3, dx = tap % 3;
    bf16x8 aF[2];
#pragma unroll
    for (int g = 0; g < 2; ++g) {
      int co = wvCout + g * 16 + l15;
      aF[g] = *(const bf16x8*)(wT + (size_t)co * K + tap * CIN + l4 * 8);
    }
    const int tb = (dy * 18 + dx + l15) * 32 + l4 * 8;
#pragma unroll
    for (int pt = 0; pt < PH; ++pt) {
      int off = tb + pt * (18 * 32);
      bf16x8 bh = *(const bf16x8*)(hiT + off);
      bf16x8 bl = *(const bf16x8*)(loT + off);
      acc[0][pt] = __builtin_amdgcn_mfma_f32_16x16x32_bf16(aF[0], bh, acc[0][pt], 0, 0, 0);
      acc[1][pt] = __builtin_amdgcn_mfma_f32_16x16x32_bf16(aF[1], bh, acc[1][pt], 0, 0, 0);
      acc[0][pt] = __builtin_amdgcn_mfma_f32_16x16x32_bf16(aF[0], bl, acc[0][pt], 0, 0, 0);
      acc[1][pt] = __builtin_amdgcn_mfma_f32_16x16x32_bf16(aF[1], bl, acc[1][pt], 0, 0, 0);
    }
  }
}

// layer 1 pass 1: partials only (z never materialized)
__global__ __launch_bounds__(128) void conv1_mfma_stats(const float* __restrict__ inNHWC,
                                                        const unsigned short* __restrict__ wT,
                                                        double* __restrict__ pS,
                                                        double* __restrict__ pQ) {
  __shared__ unsigned short hiT[10 * 18 * 32];
  __shared__ unsigned short loT[10 * 18 * 32];
  const int bx = blockIdx.x;
  const int tX = bx & 7, tY = bx >> 3;
  const int n = blockIdx.z;
  const int wave = threadIdx.x >> 6;
  const int wvCout = wave * 32;
  f32x4 acc[2][8];
  conv1_body<8, 2>(inNHWC, wT, wvCout, n, tX * 16, tY * 8, hiT, loT, acc);
  bn_partials<8>(acc, wvCout, 64, n * gridDim.x + bx, pS, pQ);
}

// layer 1 pass 2: recompute, BN+relu+2x2 maxpool, write pooled NHWC directly
__global__ __launch_bounds__(128) void conv1_mfma_pool(const float* __restrict__ inNHWC,
                                                       const unsigned short* __restrict__ wT,
                                                       const float* __restrict__ scsh,
                                                       float* __restrict__ outNHWC) {
  __shared__ unsigned short hiT[10 * 18 * 32];
  __shared__ unsigned short loT[10 * 18 * 32];
  const int bx = blockIdx.x;
  const int tX = bx & 7, tY = bx >> 3;
  const int n = blockIdx.z;
  const int wave = threadIdx.x >> 6, lane = threadIdx.x & 63;
  const int l15 = lane & 15, l4 = lane >> 4;
  const int wvCout = wave * 32;
  const int x0 = tX * 16, y0 = tY * 8;
  f32x4 acc[2][8];
  conv1_body<8, 2>(inNHWC, wT, wvCout, n, x0, y0, hiT, loT, acc);
#pragma unroll
  for (int g = 0; g < 2; ++g) {
    const int co0 = wvCout + g * 16 + l4 * 4;
#pragma unroll
    for (int pt = 0; pt < 8; pt += 2) {
      float m[4];
#pragma unroll
      for (int r = 0; r < 4; ++r) {
        float sc = scsh[co0 + r], sh = scsh[64 + co0 + r];
        float v0 = fmaxf(fmaf(acc[g][pt][r], sc, sh), 0.f);
        float v1 = fmaxf(fmaf(acc[g][pt + 1][r], sc, sh), 0.f);
        float a = fmaxf(v0, v1);
        m[r] = fmaxf(a, __shfl_xor(a, 1));
      }
      if ((l15 & 1) == 0) {
        int oy = (y0 + pt) >> 1, ox = (x0 + l15) >> 1;
        *(float4*)(outNHWC + ((((size_t)n * 64 + oy) * 64 + ox) << 6) + co0) =
            make_float4(m[0], m[1], m[2], m[3]);
      }
    }
  }
}

// ---------------- fused norm+relu+pool (fp32 z in, NCHW out) ----------------
__global__ __launch_bounds__(256) void bn_pool(const float* __restrict__ y,
                                               const float* __restrict__ scsh, int C, int lw,
                                               int lh, int lc, int N, float* __restrict__ out) {
  const int Wo = 1 << lw, Ho = 1 << lh;
  const int total = (N << lc) << (lw + lh);
  const int Wrow = 1 << (lw + 1);
  for (int i = blockIdx.x * 256 + threadIdx.x; i < total; i += gridDim.x * 256) {
    int wo = i & (Wo - 1);
    int ho = (i >> lw) & (Ho - 1);
    int c = (i >> (lw + lh)) & (C - 1);
    int n = i >> (lw + lh + lc);
    float sc = scsh[c], sh = scsh[C + c];
    size_t idx = (((((size_t)n * C + c) << (lh + 1)) + (ho << 1)) << (lw + 1)) + (wo << 1);
    float z00 = fmaxf(fmaf(y[idx], sc, sh), 0.f);
    float z01 = fmaxf(fmaf(y[idx + 1], sc, sh), 0.f);
    float z10 = fmaxf(fmaf(y[idx + Wrow], sc, sh), 0.f);
    float z11 = fmaxf(fmaf(y[idx + Wrow + 1], sc, sh), 0.f);
    out[i] = fmaxf(fmaxf(z00, z01), fmaxf(z10, z11));
  }
}

// ---------------- pooled4 fp32 -> hi/lo bf16 ----------------
__global__ __launch_bounds__(256) void hilo_split(const float* __restrict__ in,
                                                  unsigned short* __restrict__ hi,
                                                  unsigned short* __restrict__ lo, int n) {
  int i = blockIdx.x * 256 + threadIdx.x;
  if (i >= n) return;
  float f = in[i];
  __hip_bfloat16 h = __float2bfloat16(f);
  unsigned short hu;
  __builtin_memcpy(&hu, &h, 2);
  hi[i] = hu;
  lo[i] = f2us(f - __bfloat162float(h));
}

// ---------------- FC1 MFMA GEMM: A = int8 codes converted in-register ----------------
DEV bf16x8 i8_to_bf16x8(i8x8 v) {
  us8 u;
#pragma unroll
  for (int j = 0; j < 8; ++j) {
    int c = v[j];
    u[j] = (unsigned short)(c == 0 ? 0 : (c > 0 ? 0x3F80 : 0xBF80));
  }
  bf16x8 r;
  __builtin_memcpy(&r, &u, 16);
  return r;
}

// grid (8 o-blocks, 128 k-slices of 256) = 1024 blocks (was 256 @ 12.5% occupancy)
__global__ __launch_bounds__(256) void fc1_mfma(const int8_t* __restrict__ c1,
                                                const unsigned short* __restrict__ aHi,
                                                const unsigned short* __restrict__ aLo,
                                                float* __restrict__ partial) {
  const int w = threadIdx.x >> 6, lane = threadIdx.x & 63;
  const int l15 = lane & 15, l4 = lane >> 4;
  const int o0 = blockIdx.x * 128 + w * 32;
  const int s = blockIdx.y;
  const int kbase = s * 256 + l4 * 8;
  f32x4 acc[2][2];
#pragma unroll
  for (int g = 0; g < 2; ++g)
#pragma unroll
    for (int t = 0; t < 2; ++t) acc[g][t] = (f32x4){0.f, 0.f, 0.f, 0.f};
#pragma unroll 2
  for (int kc = 0; kc < 256; kc += 32) {
    bf16x8 a0 = i8_to_bf16x8(*(const i8x8*)(c1 + (size_t)(o0 + l15) * 32768 + kbase + kc));
    bf16x8 a1 = i8_to_bf16x8(*(const i8x8*)(c1 + (size_t)(o0 + 16 + l15) * 32768 + kbase + kc));
    bf16x8 bh0 = *(const bf16x8*)(aHi + (size_t)l15 * 32768 + kbase + kc);
    bf16x8 bl0 = *(const bf16x8*)(aLo + (size_t)l15 * 32768 + kbase + kc);
    bf16x8 bh1 = *(const bf16x8*)(aHi + (size_t)(16 + l15) * 32768 + kbase + kc);
    bf16x8 bl1 = *(const bf16x8*)(aLo + (size_t)(16 + l15) * 32768 + kbase + kc);
    acc[0][0] = __builtin_amdgcn_mfma_f32_16x16x32_bf16(a0, bh0, acc[0][0], 0, 0, 0);
    acc[0][0] = __builtin_amdgcn_mfma_f32_16x16x32_bf16(a0, bl0, acc[0][0], 0, 0, 0);
    acc[1][0] = __builtin_amdgcn_mfma_f32_16x16x32_bf16(a1, bh0, acc[1][0], 0, 0, 0);
    acc[1][0] = __builtin_amdgcn_mfma_f32_16x16x32_bf16(a1, bl0, acc[1][0], 0, 0, 0);
    acc[0][1] = __builtin_amdgcn_mfma_f32_16x16x32_bf16(a0, bh1, acc[0][1], 0, 0, 0);
    acc[0][1] = __builtin_amdgcn_mfma_f32_16x16x32_bf16(a0, bl1, acc[0][1], 0, 0, 0);
    acc[1][1] = __builtin_amdgcn_mfma_f32_16x16x32_bf16(a1, bh1, acc[1][1], 0, 0, 0);
    acc[1][1] = __builtin_amdgcn_mfma_f32_16x16x32_bf16(a1, bl1, acc[1][1], 0, 0, 0);
  }
#pragma unroll
  for (int g = 0; g < 2; ++g)
#pragma unroll
    for (int t = 0; t < 2; ++t)
#pragma unroll
      for (int r = 0; r < 4; ++r) {
        int o = o0 + g * 16 + l4 * 4 + r;
        int n = t * 16 + l15;
        partial[((size_t)s * 1024 + o) * 32 + n] = acc[g][t][r];
      }
}

__global__ __launch_bounds__(256) void fc1_fin(const float* __restrict__ partial,
                                               const double* __restrict__ st,
                                               const float* __restrict__ fb,
                                               float* __restrict__ fc1T) {
  int i = blockIdx.x * 256 + threadIdx.x;  // 32768
  int o = i >> 5;
  float s = 0.f;
#pragma unroll 8
  for (int t = 0; t < 128; ++t) s += partial[(size_t)t * 32768 + i];
  float alpha = tern_alpha_d(st, 33554432.0);
  fc1T[i] = fmaxf(fmaf(s, alpha, fb[o]), 0.f);
}

// ---------------- FC2 (row-parallel; tiny) ----------------
__global__ __launch_bounds__(256) void fc2_kernel(const float* __restrict__ xT,
                                                  const int8_t* __restrict__ codes,
                                                  const double* __restrict__ st,
                                                  const float* __restrict__ fb,
                                                  float* __restrict__ out) {
  const int o = blockIdx.x;
  float acc[32];
#pragma unroll
  for (int j = 0; j < 32; ++j) acc[j] = 0.f;
  const int8_t* crow = codes + (size_t)o * 1024;
  for (int k = threadIdx.x; k < 1024; k += 256) {
    int cv = crow[k];
    if (cv != 0) {
      float c = (float)cv;
      const float4* pv = (const float4*)(xT + ((size_t)k << 5));
#pragma unroll
      for (int j = 0; j < 8; ++j) {
        float4 v = pv[j];
        acc[4 * j + 0] = fmaf(c, v.x, acc[4 * j + 0]);
        acc[4 * j + 1] = fmaf(c, v.y, acc[4 * j + 1]);
        acc[4 * j + 2] = fmaf(c, v.z, acc[4 * j + 2]);
        acc[4 * j + 3] = fmaf(c, v.w, acc[4 * j + 3]);
      }
    }
  }
#pragma unroll
  for (int j = 0; j < 32; ++j) {
#pragma unroll
    for (int off = 32; off > 0; off >>= 1) acc[j] += __shfl_down(acc[j], off);
  }
  __shared__ float red[4][32];
  int lane = threadIdx.x & 63, wv = threadIdx.x >> 6;
  if (lane == 0) {
#pragma unroll
    for (int j = 0; j < 32; ++j) red[wv][j] = acc[j];
  }
  __syncthreads();
  if (threadIdx.x < 32) {
    int n = threadIdx.x;
    float alpha = tern_alpha_d(st, 1024000.0);
    out[(size_t)n * 1000 + o] = (red[0][n] + red[1][n] + red[2][n] + red[3][n]) * alpha + fb[o];
  }
}

// ---------------- host ----------------
extern "C" void kernel_launch(void* const* d_in, const int* in_sizes, int n_in, void* d_out,
                              int out_size, void* d_ws, size_t ws_size, hipStream_t stream) {
  const float* x = (const float*)d_in[0];
  const float* w1 = (const float*)d_in[1];
  const float* g1 = (const float*)d_in[3];
  const float* be1 = (const float*)d_in[4];
  const float* w2 = (const float*)d_in[5];
  const float* g2 = (const float*)d_in[7];
  const float* be2 = (const float*)d_in[8];
  const float* w3 = (const float*)d_in[9];
  const float* g3 = (const float*)d_in[11];
  const float* be3 = (const float*)d_in[12];
  const float* w4 = (const float*)d_in[13];
  const float* g4 = (const float*)d_in[15];
  const float* be4 = (const float*)d_in[16];
  const float* fw1 = (const float*)d_in[17];
  const float* fb1 = (const float*)d_in[18];
  const float* fw2 = (const float*)d_in[19];
  const float* fb2 = (const float*)d_in[20];
  // b1..b4 cancel exactly under training-mode BN (alpha-folded finalize).
  (void)in_sizes; (void)n_in; (void)out_size; (void)ws_size;

  char* ws = (char*)d_ws;
  size_t off = 0;
  auto alloc = [&](size_t bytes) {
    size_t o = off;
    off += (bytes + 255) & ~(size_t)255;
    return o;
  };
  unsigned short* wb1 = (unsigned short*)(ws + alloc((size_t)18432 * 2));    // [64][288]
  unsigned short* wb2 = (unsigned short*)(ws + alloc((size_t)73728 * 2));    // [128][576]
  unsigned short* wb3 = (unsigned short*)(ws + alloc((size_t)294912 * 2));   // [256][1152]
  unsigned short* wb4 = (unsigned short*)(ws + alloc((size_t)1179648 * 2));  // [512][2304]
  int8_t* c1 = (int8_t*)(ws + alloc((size_t)33554432));  // fc1 int8 codes [1024][32768]
  int8_t* c2 = (int8_t*)(ws + alloc((size_t)1024000));
  // st (32 doubles) + 64-bucket partials for {abs, ms, cnt} x 6 tensors
  double* dst = (double*)(ws + alloc((size_t)(32 + 3 * 384) * 8));
  double* absB = dst + 32;
  double* msB = absB + 384;
  double* cntB = msB + 384;
  float* scsh = (float*)(ws + alloc((size_t)4096 * 4));
  double* pS = (double*)(ws + alloc((size_t)524288 * 8));  // L2 needs P=4096 x C=128
  double* pQ = (double*)(ws + alloc((size_t)524288 * 8));
  float* bufY = (float*)(ws + alloc((size_t)16777216 * 4));  // 67MB: x32pad / z / fc1part
  float* bufA = (float*)(ws + alloc((size_t)8388608 * 4));   // 33.5MB: pooled NCHW+NHWC
  unsigned short* actHi = (unsigned short*)(ws + alloc((size_t)1048576 * 2));
  unsigned short* actLo = (unsigned short*)(ws + alloc((size_t)1048576 * 2));
  float* fc1T = (float*)(ws + alloc((size_t)32768 * 4));  // [1024][32]
  float* x32 = bufY;              // NHWC-32 input, dead after conv1
  float* bufA2 = bufA + 4194304;  // second half for NHWC copies
  float* fc1part = bufY;          // [128][1024][32] = 16 MB; bufY dead by FC time

  hipMemsetAsync(dst, 0, (32 + 3 * 384) * 8, stream);

  // ternarize stats: flat proportional grid (exact-fit block ranges).
  TDescs ta;
  ta.d[0] = {fw1, 33554432, 0, 8192, 4};
  ta.d[1] = {w4, 1179648, 8192, 288, 3};
  ta.d[2] = {fw2, 1024000, 8480, 250, 5};
  ta.d[3] = {w3, 294912, 8730, 72, 2};
  ta.d[4] = {w2, 73728, 8802, 18, 1};
  ta.d[5] = {w1, 1728, 8820, 1, 0};
  tern_abs_all<<<8821, 256, 0, stream>>>(ta, absB);
  MDescs tm;
  tm.d[0] = {fw1, c1, 33554432, 0, 8192, 4};
  tm.d[1] = {w4, nullptr, 1179648, 8192, 288, 3};
  tm.d[2] = {fw2, c2, 1024000, 8480, 250, 5};
  tm.d[3] = {w3, nullptr, 294912, 8730, 72, 2};
  tm.d[4] = {w2, nullptr, 73728, 8802, 18, 1};
  tm.d[5] = {w1, nullptr, 1728, 8820, 1, 0};
  tern_masked_code_all<<<8821, 256, 0, stream>>>(tm, absB, msB, cntB);
  tern_collapse<<<6, 64, 0, stream>>>(absB, msB, cntB, dst);
  tern_write_convb_pad<<<72, 256, 0, stream>>>(w1, absB + 0 * 64, wb1);
  tern_write_convb<<<288, 256, 0, stream>>>(w2, absB + 1 * 64, 73728, 64, wb2);
  tern_write_convb<<<1152, 256, 0, stream>>>(w3, absB + 2 * 64, 294912, 128, wb3);
  tern_write_convb<<<4608, 256, 0, stream>>>(w4, absB + 3 * 64, 1179648, 256, wb4);

  float* ss1 = scsh;
  float* ss2 = scsh + 128;
  float* ss3 = scsh + 512;
  float* ss4 = scsh + 1024;

  // Layer 1 via MFMA, two-pass recompute; pooled1 written directly as NHWC.
  pad32<<<2048, 256, 0, stream>>>(x, x32);
  conv1_mfma_stats<<<dim3(128, 1, 32), 128, 0, stream>>>(x32, wb1, pS, pQ);
  bn_fin_alpha<<<64, 256, 0, stream>>>(pS, pQ, 4096, g1, be1, 524288.0, dst + 0, 1728.0, ss1,
                                       64);
  conv1_mfma_pool<<<dim3(128, 1, 32), 128, 0, stream>>>(x32, wb1, ss1, bufA);

  // Layer 2: 64->128 @64x64, split-K 8-wave blocks (z -> bufY)
  conv_ks<64, 64><<<dim3(128, 1, 32), 512, 0, stream>>>(bufA, wb2, bufY, 128, pS, pQ);
  bn_fin_alpha<<<128, 256, 0, stream>>>(pS, pQ, 4096, g2, be2, 131072.0, dst + 4, 73728.0, ss2,
                                        128);
  bn_pool<<<16384, 256, 0, stream>>>(bufY, ss2, 128, 5, 5, 7, 32, bufA);
  nchw2nhwc<<<dim3(2, 16, 32), 256, 0, stream>>>(bufA, bufA2, 128, 1024);

  // Layer 3: 128->256 @32x32
  conv_ks<128, 32><<<dim3(32, 2, 32), 512, 0, stream>>>(bufA2, wb3, bufY, 256, pS, pQ);
  bn_fin_alpha<<<256, 256, 0, stream>>>(pS, pQ, 1024, g3, be3, 32768.0, dst + 8, 294912.0, ss3,
                                        256);
  bn_pool<<<8192, 256, 0, stream>>>(bufY, ss3, 256, 4, 4, 8, 32, bufA);
  nchw2nhwc<<<dim3(4, 4, 32), 256, 0, stream>>>(bufA, bufA2, 256, 256);

  // Layer 4: 256->512 @16x16; pooled4 NCHW flat == [32][32768]
  conv_ks<256, 16><<<dim3(8, 4, 32), 512, 0, stream>>>(bufA2, wb4, bufY, 512, pS, pQ);
  bn_fin_alpha<<<512, 256, 0, stream>>>(pS, pQ, 256, g4, be4, 8192.0, dst + 12, 1179648.0, ss4,
                                        512);
  bn_pool<<<4096, 256, 0, stream>>>(bufY, ss4, 512, 3, 3, 9, 32, bufA);
  hilo_split<<<4096, 256, 0, stream>>>(bufA, actHi, actLo, 1048576);

  // FC1 (int8 codes -> in-register bf16), 1024 blocks; then finalize + FC2
  fc1_mfma<<<dim3(8, 128), 256, 0, stream>>>(c1, actHi, actLo, fc1part);
  fc1_fin<<<128, 256, 0, stream>>>(fc1part, dst + 16, fb1, fc1T);
  fc2_kernel<<<1000, 256, 0, stream>>>(fc1T, c2, dst + 20, fb2, (float*)d_out);
}

// Round 6
// 607.194 us; speedup vs baseline: 1.4638x; 1.4638x over previous
//
#include <hip/hip_runtime.h>
#include <hip/hip_bf16.h>
#include <stdint.h>

#define DEV __device__ __forceinline__

typedef __bf16 bf16x8 __attribute__((ext_vector_type(8)));
typedef float f32x4 __attribute__((ext_vector_type(4)));
typedef unsigned short us8 __attribute__((ext_vector_type(8)));
typedef int8_t i8x8 __attribute__((ext_vector_type(8)));

DEV unsigned short f2us(float f) {
  __hip_bfloat16 h = __float2bfloat16(f);
  unsigned short u;
  __builtin_memcpy(&u, &h, 2);
  return u;
}

DEV double wave_reduce_d(double v) {
#pragma unroll
  for (int off = 32; off > 0; off >>= 1) v += __shfl_down(v, off);
  return v;
}

DEV double dbl_block_reduce(double v, double* lds) {
  v = wave_reduce_d(v);
  int lane = threadIdx.x & 63, w = threadIdx.x >> 6;
  if (lane == 0) lds[w] = v;
  __syncthreads();
  double r = 0.0;
  if (threadIdx.x == 0) r = lds[0] + lds[1] + lds[2] + lds[3];
  __syncthreads();
  return r;
}

// ---------------- ternarize: fp64 stats, flat proportional grid ----------------
struct TDesc { const float* w; int n; int b0; int nb; int slot; };
struct TDescs { TDesc d[6]; };

DEV double abs4d(float4 v) {
  return fabs((double)v.x) + fabs((double)v.y) + fabs((double)v.z) + fabs((double)v.w);
}

DEV double bucket_sum64(const double* b) {
  double s = 0.0;
#pragma unroll
  for (int j = 0; j < 64; ++j) s += b[j];
  return s;
}

__global__ __launch_bounds__(256) void tern_abs_all(TDescs td, double* __restrict__ absB) {
  __shared__ double lds[4];
  const int b = blockIdx.x;
  int k = 0;
  while (k < 5 && b >= td.d[k + 1].b0) ++k;  // d[] sorted ascending by b0
  const TDesc D = td.d[k];
  const float4* w4 = (const float4*)D.w;
  const int n4 = D.n >> 2;
  const int S = D.nb * 256;
  int i = (b - D.b0) * 256 + threadIdx.x;
  double s0 = 0.0, s1 = 0.0, s2 = 0.0, s3 = 0.0;
  for (; i + 3 * S < n4; i += 4 * S) {
    float4 v0 = w4[i];
    float4 v1 = w4[i + S];
    float4 v2 = w4[i + 2 * S];
    float4 v3 = w4[i + 3 * S];
    s0 += abs4d(v0);
    s1 += abs4d(v1);
    s2 += abs4d(v2);
    s3 += abs4d(v3);
  }
  for (; i < n4; i += S) s0 += abs4d(w4[i]);
  double s = (s0 + s1) + (s2 + s3);
  s = dbl_block_reduce(s, lds);
  if (threadIdx.x == 0 && s != 0.0) atomicAdd(absB + D.slot * 64 + (b & 63), s);
}

struct MDesc { const float* w; int8_t* out; int n; int b0; int nb; int slot; };
struct MDescs { MDesc d[6]; };

DEV int proc4(float4 v, double delta, double& ms, int& cnt) {
  float e[4] = {v.x, v.y, v.z, v.w};
  char pk[4];
#pragma unroll
  for (int j = 0; j < 4; ++j) {
    double d = (double)e[j];
    double a = fabs(d);
    if (a > delta) { ms += a; cnt += 1; }
    pk[j] = (char)((d > delta) ? 1 : ((d < -delta) ? -1 : 0));
  }
  int w32;
  __builtin_memcpy(&w32, pk, 4);
  return w32;
}

__global__ __launch_bounds__(256) void tern_masked_code_all(MDescs td,
                                                            const double* __restrict__ absB,
                                                            double* __restrict__ msB,
                                                            double* __restrict__ cntB) {
  __shared__ double lds[4];
  const int b = blockIdx.x;
  int k = 0;
  while (k < 5 && b >= td.d[k + 1].b0) ++k;
  const MDesc D = td.d[k];
  const float4* w4 = (const float4*)D.w;
  int8_t* out = D.out;
  const int n4 = D.n >> 2;
  const double delta = 0.7 * bucket_sum64(absB + D.slot * 64) / (double)D.n;
  const int S = D.nb * 256;
  int i = (b - D.b0) * 256 + threadIdx.x;
  double m0 = 0.0, m1 = 0.0, m2 = 0.0, m3 = 0.0;
  int c0 = 0, c1x = 0, c2x = 0, c3 = 0;
  for (; i + 3 * S < n4; i += 4 * S) {
    float4 v0 = w4[i];
    float4 v1 = w4[i + S];
    float4 v2 = w4[i + 2 * S];
    float4 v3 = w4[i + 3 * S];
    int p0 = proc4(v0, delta, m0, c0);
    int p1 = proc4(v1, delta, m1, c1x);
    int p2 = proc4(v2, delta, m2, c2x);
    int p3 = proc4(v3, delta, m3, c3);
    if (out) {
      *(int*)(out + ((size_t)i << 2)) = p0;
      *(int*)(out + ((size_t)(i + S) << 2)) = p1;
      *(int*)(out + ((size_t)(i + 2 * S) << 2)) = p2;
      *(int*)(out + ((size_t)(i + 3 * S) << 2)) = p3;
    }
  }
  for (; i < n4; i += S) {
    int p = proc4(w4[i], delta, m0, c0);
    if (out) *(int*)(out + ((size_t)i << 2)) = p;
  }
  double ms = (m0 + m1) + (m2 + m3);
  double cnt = (double)(c0 + c1x + c2x + c3);
  ms = dbl_block_reduce(ms, lds);
  cnt = dbl_block_reduce(cnt, lds);
  if (threadIdx.x == 0 && cnt != 0.0) {
    atomicAdd(msB + D.slot * 64 + (b & 63), ms);
    atomicAdd(cntB + D.slot * 64 + (b & 63), cnt);
  }
}

__global__ __launch_bounds__(64) void tern_collapse(const double* __restrict__ absB,
                                                    const double* __restrict__ msB,
                                                    const double* __restrict__ cntB,
                                                    double* __restrict__ st) {
  const int t = blockIdx.x;
  const int lane = threadIdx.x;
  double a = absB[t * 64 + lane];
  double m = msB[t * 64 + lane];
  double c = cntB[t * 64 + lane];
#pragma unroll
  for (int off = 32; off > 0; off >>= 1) {
    a += __shfl_down(a, off);
    m += __shfl_down(m, off);
    c += __shfl_down(c, off);
  }
  if (lane == 0) {
    st[t * 4] = a;
    st[t * 4 + 1] = m;
    st[t * 4 + 2] = c;
  }
}

DEV float tern_alpha_d(const double* st, double n) {
  double cnt = st[2];
  return (float)(cnt > 0.0 ? st[1] / fmax(cnt, 1.0) : st[0] / n);
}
DEV double tern_alpha_dd(const double* st, double n) {
  double cnt = st[2];
  return cnt > 0.0 ? st[1] / fmax(cnt, 1.0) : st[0] / n;
}

// conv2-4 weights -> bf16 codes {-1,0,+1}, layout [cout][k=tap*CIN+ci]
__global__ __launch_bounds__(256) void tern_write_convb(const float* __restrict__ w,
                                                        const double* __restrict__ ab, int total,
                                                        int CIN, unsigned short* __restrict__ out) {
  int i = blockIdx.x * 256 + threadIdx.x;
  if (i >= total) return;
  double delta = 0.7 * bucket_sum64(ab) / (double)total;
  double v = (double)w[i];
  float code = v > delta ? 1.f : (v < -delta ? -1.f : 0.f);
  int cin9 = CIN * 9;
  int o = i / cin9, rem = i - o * cin9;
  int ci = rem / 9, tap = rem - ci * 9;
  out[(size_t)o * cin9 + tap * CIN + ci] = f2us(code);
}

// conv1 weights: im2col-27 layout [64 cout][k=dy*9+dx*3+ci, pad 27..31 = 0]
__global__ __launch_bounds__(256) void tern_write_convb_pad(const float* __restrict__ w,
                                                            const double* __restrict__ ab,
                                                            unsigned short* __restrict__ out) {
  int i = blockIdx.x * 256 + threadIdx.x;
  if (i >= 64 * 32) return;
  int o = i >> 5, k = i & 31;
  float code = 0.f;
  if (k < 27) {
    int dy = k / 9, r = k - dy * 9, dx = r / 3, ci = r - dx * 3;
    int tap = dy * 3 + dx;
    double delta = 0.7 * bucket_sum64(ab) / 1728.0;
    double v = (double)w[(o * 3 + ci) * 9 + tap];
    code = v > delta ? 1.f : (v < -delta ? -1.f : 0.f);
  }
  out[i] = f2us(code);
}

// ---------------- BN finalize (alpha-folded; bias cancels exactly) ----------------
// pS/pQ layout [p][co] (coalesced writes from conv)
__global__ __launch_bounds__(256) void bn_fin_alpha(const double* __restrict__ pS,
                                                    const double* __restrict__ pQ, int P,
                                                    const float* __restrict__ g,
                                                    const float* __restrict__ be, double M,
                                                    const double* __restrict__ st, double nels,
                                                    float* __restrict__ scsh, int C) {
  __shared__ double lds[4];
  const int c = blockIdx.x;
  double s = 0.0, q = 0.0;
  for (int p = threadIdx.x; p < P; p += 256) {
    s += pS[(size_t)p * C + c];
    q += pQ[(size_t)p * C + c];
  }
  s = dbl_block_reduce(s, lds);
  q = dbl_block_reduce(q, lds);
  if (threadIdx.x == 0) {
    double al = tern_alpha_dd(st, nels);
    double mean = s / M;
    double var = q / M - mean * mean;
    double sc = (double)g[c] * al / sqrt(al * al * var + 1e-5);
    scsh[c] = (float)sc;
    scsh[C + c] = (float)((double)be[c] - mean * sc);
  }
}

// ---------------- hi/lo bf16 split helper ----------------
DEV void cvt8(float4 a, float4 b, us8& hv, us8& lv) {
  float f[8] = {a.x, a.y, a.z, a.w, b.x, b.y, b.z, b.w};
#pragma unroll
  for (int e = 0; e < 8; ++e) {
    __hip_bfloat16 h = __float2bfloat16(f[e]);
    unsigned short hu;
    __builtin_memcpy(&hu, &h, 2);
    hv[e] = hu;
    lv[e] = f2us(f[e] - __bfloat162float(h));
  }
}

// fused fp64 BN partial write (per wave, 16-lane reduce), layout [p][co]
template <int PH>
DEV void bn_partials(const f32x4 (&acc)[2][PH], int wvCout, int CO, int p,
                     double* __restrict__ pS, double* __restrict__ pQ) {
  const int lane = threadIdx.x & 63;
  const int l15 = lane & 15, l4 = lane >> 4;
#pragma unroll
  for (int g = 0; g < 2; ++g) {
    float sv[4] = {0, 0, 0, 0}, qv[4] = {0, 0, 0, 0};
#pragma unroll
    for (int pt = 0; pt < PH; ++pt)
#pragma unroll
      for (int r = 0; r < 4; ++r) {
        float v = acc[g][pt][r];
        sv[r] += v;
        qv[r] = fmaf(v, v, qv[r]);
      }
#pragma unroll
    for (int r = 0; r < 4; ++r)
#pragma unroll
      for (int m = 1; m < 16; m <<= 1) {
        sv[r] += __shfl_xor(sv[r], m);
        qv[r] += __shfl_xor(qv[r], m);
      }
    if (l15 == 0) {
#pragma unroll
      for (int r = 0; r < 4; ++r) {
        int co = wvCout + g * 16 + l4 * 4 + r;
        pS[(size_t)p * CO + co] = (double)sv[r];
        pQ[(size_t)p * CO + co] = (double)qv[r];
      }
    }
  }
}

// ---------------- MFMA tap loop (layers 2-4) ----------------
template <int CIN, int PH>
DEV void mfma_phase(const unsigned short* __restrict__ wT, const unsigned short* hC,
                    const unsigned short* lC, int wvCout, int cc, int l15, int l4,
                    f32x4 (&acc)[2][PH]) {
  constexpr int K = 9 * CIN;
#pragma unroll
  for (int tap = 0; tap < 9; ++tap) {
    const int dy = tap / 3, dx = tap % 3;
    bf16x8 aF[2];
#pragma unroll
    for (int g = 0; g < 2; ++g) {
      int co = wvCout + g * 16 + l15;
      aF[g] = *(const bf16x8*)(wT + (size_t)co * K + tap * CIN + cc * 32 + l4 * 8);
    }
    const int tb = (dy * 18 + dx + l15) * 32 + l4 * 8;
#pragma unroll
    for (int pt = 0; pt < PH; ++pt) {
      int off = tb + pt * (18 * 32);
      bf16x8 bh = *(const bf16x8*)(hC + off);
      bf16x8 bl = *(const bf16x8*)(lC + off);
      acc[0][pt] = __builtin_amdgcn_mfma_f32_16x16x32_bf16(aF[0], bh, acc[0][pt], 0, 0, 0);
      acc[1][pt] = __builtin_amdgcn_mfma_f32_16x16x32_bf16(aF[1], bh, acc[1][pt], 0, 0, 0);
      acc[0][pt] = __builtin_amdgcn_mfma_f32_16x16x32_bf16(aF[0], bl, acc[0][pt], 0, 0, 0);
      acc[1][pt] = __builtin_amdgcn_mfma_f32_16x16x32_bf16(aF[1], bl, acc[1][pt], 0, 0, 0);
    }
  }
}

// layers 2-4: R1 geometry (4-wave, PH=8/4/2, single-buffer LDS) + R2's register
// prefetch under a 2-barrier/chunk discipline.  z store (NCHW) + BN partials.
template <int CIN, int H, int PH>
__global__ __launch_bounds__(256) void conv_mfma(const float* __restrict__ inNHWC,
                                                 const unsigned short* __restrict__ wT,
                                                 float* __restrict__ z, int COUT,
                                                 double* __restrict__ pS,
                                                 double* __restrict__ pQ) {
  constexpr int W = H;
  constexpr int CH = CIN / 32;
  constexpr int TX = W / 16;
  constexpr int NU = (PH + 2) * 18 * 4;
  constexpr int T = 256;
  constexpr int UPT = (NU + T - 1) / T;
  constexpr int TILE = (PH + 2) * 18 * 32;
  __shared__ unsigned short hiT[TILE];
  __shared__ unsigned short loT[TILE];
  const int bx = blockIdx.x;
  const int tX = bx % TX, tY = bx / TX;
  const int n = blockIdx.z;
  const int wave = threadIdx.x >> 6, lane = threadIdx.x & 63;
  const int l15 = lane & 15, l4 = lane >> 4;
  const int wvCout = blockIdx.y * 128 + wave * 32;
  const int x0 = tX * 16, y0 = tY * PH;

  f32x4 acc[2][PH];
#pragma unroll
  for (int g = 0; g < 2; ++g)
#pragma unroll
    for (int pt = 0; pt < PH; ++pt) acc[g][pt] = (f32x4){0.f, 0.f, 0.f, 0.f};

  // cc-independent staging descriptors
  const float* srcB[UPT];
  int ldsO[UPT];
  bool inb[UPT];
#pragma unroll
  for (int j = 0; j < UPT; ++j) {
    int u = threadIdx.x + j * T;
    int q = u & 3, rem = u >> 2;
    int xx = rem % 18, yy = rem / 18;
    int gy = y0 + yy - 1, gx = x0 + xx - 1;
    bool ok = (u < NU) && ((unsigned)gy < (unsigned)H) && ((unsigned)gx < (unsigned)W);
    inb[j] = ok;
    int cy = ok ? gy : 0, cx = ok ? gx : 0;
    srcB[j] = inNHWC + (((size_t)(n * H + cy) * W + cx) * CIN + q * 8);
    ldsO[j] = (rem << 5) + (q << 3);
  }
  float4 pa[UPT], pb[UPT];
#pragma unroll
  for (int j = 0; j < UPT; ++j)
    if (inb[j]) {
      pa[j] = *(const float4*)srcB[j];
      pb[j] = *(const float4*)(srcB[j] + 4);
    }
#pragma unroll 1
  for (int cc = 0; cc < CH; ++cc) {
    if (cc) {  // all waves done reading LDS of chunk cc-1
      asm volatile("s_waitcnt lgkmcnt(0)" ::: "memory");
      __builtin_amdgcn_s_barrier();
      __builtin_amdgcn_sched_barrier(0);
    }
#pragma unroll
    for (int j = 0; j < UPT; ++j) {
      int u = threadIdx.x + j * T;
      if (u < NU) {
        us8 hv = (us8)0, lv = (us8)0;
        if (inb[j]) cvt8(pa[j], pb[j], hv, lv);
        *(us8*)(hiT + ldsO[j]) = hv;
        *(us8*)(loT + ldsO[j]) = lv;
      }
    }
    asm volatile("s_waitcnt lgkmcnt(0)" ::: "memory");
    __builtin_amdgcn_s_barrier();
    __builtin_amdgcn_sched_barrier(0);
    // prefetch next chunk's globals; they fly under the MFMA phase (T14)
    if (cc + 1 < CH) {
#pragma unroll
      for (int j = 0; j < UPT; ++j)
        if (inb[j]) {
          pa[j] = *(const float4*)(srcB[j] + (size_t)(cc + 1) * 32);
          pb[j] = *(const float4*)(srcB[j] + (size_t)(cc + 1) * 32 + 4);
        }
    }
    mfma_phase<CIN, PH>(wT, hiT, loT, wvCout, cc, l15, l4, acc);
  }

#pragma unroll
  for (int g = 0; g < 2; ++g)
#pragma unroll
    for (int pt = 0; pt < PH; ++pt) {
      int oy = y0 + pt;
#pragma unroll
      for (int r = 0; r < 4; ++r) {
        int co = wvCout + g * 16 + l4 * 4 + r;
        z[(((size_t)n * COUT + co) * H + oy) * W + x0 + l15] = acc[g][pt][r];
      }
    }
  bn_partials<PH>(acc, wvCout, COUT, n * gridDim.x + bx, pS, pQ);
}

// ---------------- conv1: im2col-27 (3ch x 9taps packed into one K=32 slice) ----------
// LDS holds an fp32 [(PH+2)][18][3] input tile (2.2 KB).  Each lane assembles its
// B-fragment (k = dy*9+dx*3+ci = l4*8+j) from <=9 LDS floats, splits hi/lo, and
// issues 4 MFMA per pt (vs 36 in the padded-32 scheme).  Reads x NCHW directly.
DEV void conv1_core(const float* __restrict__ x, const unsigned short* __restrict__ wb,
                    int n, int x0, int y0, float* xt, f32x4 (&acc)[2][8]) {
  const int lane = threadIdx.x & 63;
  const int l15 = lane & 15, l4 = lane >> 4;
  const int wvCout = (threadIdx.x >> 6) * 32;
#pragma unroll
  for (int g = 0; g < 2; ++g)
#pragma unroll
    for (int pt = 0; pt < 8; ++pt) acc[g][pt] = (f32x4){0.f, 0.f, 0.f, 0.f};

  for (int u = threadIdx.x; u < 540; u += 128) {  // (8+2) rows x 18 x 3ch
    int yy = u / 54, rem = u - yy * 54;
    int tx = rem / 3, ci = rem - tx * 3;
    int gy = y0 + yy - 1, gx = x0 + tx - 1;
    float v = 0.f;
    if ((unsigned)gy < 128u && (unsigned)gx < 128u)
      v = x[(((size_t)n * 3 + ci) << 14) + (gy << 7) + gx];
    xt[u] = v;
  }
  asm volatile("s_waitcnt lgkmcnt(0)" ::: "memory");
  __builtin_amdgcn_s_barrier();
  __builtin_amdgcn_sched_barrier(0);

  bf16x8 aW[2];
#pragma unroll
  for (int g = 0; g < 2; ++g)
    aW[g] = *(const bf16x8*)(wb + (size_t)(wvCout + g * 16 + l15) * 32 + l4 * 8);

#pragma unroll
  for (int pt = 0; pt < 8; ++pt) {
    us8 hv = (us8)0, lv = (us8)0;
#pragma unroll
    for (int j = 0; j < 8; ++j) {
      int k = l4 * 8 + j;
      float v = 0.f;
      if (k < 27) {
        int dy = k / 9;
        int r = k - dy * 9;
        v = xt[(pt + dy) * 54 + l15 * 3 + r];
      }
      __hip_bfloat16 h = __float2bfloat16(v);
      unsigned short hu;
      __builtin_memcpy(&hu, &h, 2);
      hv[j] = hu;
      lv[j] = f2us(v - __bfloat162float(h));
    }
    bf16x8 bh, bl;
    __builtin_memcpy(&bh, &hv, 16);
    __builtin_memcpy(&bl, &lv, 16);
    acc[0][pt] = __builtin_amdgcn_mfma_f32_16x16x32_bf16(aW[0], bh, acc[0][pt], 0, 0, 0);
    acc[0][pt] = __builtin_amdgcn_mfma_f32_16x16x32_bf16(aW[0], bl, acc[0][pt], 0, 0, 0);
    acc[1][pt] = __builtin_amdgcn_mfma_f32_16x16x32_bf16(aW[1], bh, acc[1][pt], 0, 0, 0);
    acc[1][pt] = __builtin_amdgcn_mfma_f32_16x16x32_bf16(aW[1], bl, acc[1][pt], 0, 0, 0);
  }
}

// layer 1 pass 1: partials only (z never materialized)
__global__ __launch_bounds__(128) void conv1_mfma_stats(const float* __restrict__ x,
                                                        const unsigned short* __restrict__ wT,
                                                        double* __restrict__ pS,
                                                        double* __restrict__ pQ) {
  __shared__ float xt[540];
  const int bx = blockIdx.x;
  const int tX = bx & 7, tY = bx >> 3;
  const int n = blockIdx.z;
  f32x4 acc[2][8];
  conv1_core(x, wT, n, tX * 16, tY * 8, xt, acc);
  bn_partials<8>(acc, (threadIdx.x >> 6) * 32, 64, n * gridDim.x + bx, pS, pQ);
}

// layer 1 pass 2: recompute, BN+relu+2x2 maxpool, write pooled NHWC directly
__global__ __launch_bounds__(128) void conv1_mfma_pool(const float* __restrict__ x,
                                                       const unsigned short* __restrict__ wT,
                                                       const float* __restrict__ scsh,
                                                       float* __restrict__ outNHWC) {
  __shared__ float xt[540];
  const int bx = blockIdx.x;
  const int tX = bx & 7, tY = bx >> 3;
  const int n = blockIdx.z;
  const int lane = threadIdx.x & 63;
  const int l15 = lane & 15, l4 = lane >> 4;
  const int wvCout = (threadIdx.x >> 6) * 32;
  const int x0 = tX * 16, y0 = tY * 8;
  f32x4 acc[2][8];
  conv1_core(x, wT, n, x0, y0, xt, acc);
#pragma unroll
  for (int g = 0; g < 2; ++g) {
    const int co0 = wvCout + g * 16 + l4 * 4;
#pragma unroll
    for (int pt = 0; pt < 8; pt += 2) {
      float m[4];
#pragma unroll
      for (int r = 0; r < 4; ++r) {
        float sc = scsh[co0 + r], sh = scsh[64 + co0 + r];
        float v0 = fmaxf(fmaf(acc[g][pt][r], sc, sh), 0.f);
        float v1 = fmaxf(fmaf(acc[g][pt + 1][r], sc, sh), 0.f);
        float a = fmaxf(v0, v1);
        m[r] = fmaxf(a, __shfl_xor(a, 1));
      }
      if ((l15 & 1) == 0) {
        int oy = (y0 + pt) >> 1, ox = (x0 + l15) >> 1;
        *(float4*)(outNHWC + ((((size_t)n * 64 + oy) * 64 + ox) << 6) + co0) =
            make_float4(m[0], m[1], m[2], m[3]);
      }
    }
  }
}

// ---------------- fused BN+relu+pool + NCHW->NHWC transpose (L2/L3) ----------------
__global__ __launch_bounds__(256) void bn_pool_nhwc(const float* __restrict__ z,
                                                    const float* __restrict__ scsh, int C,
                                                    int lw, float* __restrict__ out) {
  __shared__ float t[64][65];
  const int Wo = 1 << lw, Wi = Wo << 1;
  const int c0 = blockIdx.x * 64, p0 = blockIdx.y * 64, n = blockIdx.z;
  const int NP = Wo * Wo;
  for (int u = threadIdx.x; u < 4096; u += 256) {
    int cl = u >> 6, pl = u & 63;
    int pp = p0 + pl, ho = pp >> lw, wo = pp & (Wo - 1);
    int c = c0 + cl;
    size_t idx = ((size_t)(n * C + c) * Wi + (ho << 1)) * Wi + (wo << 1);
    float sc = scsh[c], sh = scsh[C + c];
    float z00 = fmaxf(fmaf(z[idx], sc, sh), 0.f);
    float z01 = fmaxf(fmaf(z[idx + 1], sc, sh), 0.f);
    float z10 = fmaxf(fmaf(z[idx + Wi], sc, sh), 0.f);
    float z11 = fmaxf(fmaf(z[idx + Wi + 1], sc, sh), 0.f);
    t[cl][pl] = fmaxf(fmaxf(z00, z01), fmaxf(z10, z11));
  }
  __syncthreads();
  for (int u = threadIdx.x; u < 4096; u += 256) {
    int pl = u >> 6, cl = u & 63;
    out[((size_t)n * NP + p0 + pl) * C + c0 + cl] = t[cl][pl];
  }
}

// ---------------- L4: fused BN+relu+pool + hi/lo split (NCHW flat out) ----------------
__global__ __launch_bounds__(256) void bn_pool_hilo(const float* __restrict__ z,
                                                    const float* __restrict__ scsh,
                                                    unsigned short* __restrict__ hi,
                                                    unsigned short* __restrict__ lo) {
  int i = blockIdx.x * 256 + threadIdx.x;  // 32*512*8*8 = 1048576
  int wo = i & 7, ho = (i >> 3) & 7, c = (i >> 6) & 511, n = i >> 15;
  float sc = scsh[c], sh = scsh[512 + c];
  size_t idx = ((size_t)(n * 512 + c) * 16 + (ho << 1)) * 16 + (wo << 1);
  float z00 = fmaxf(fmaf(z[idx], sc, sh), 0.f);
  float z01 = fmaxf(fmaf(z[idx + 1], sc, sh), 0.f);
  float z10 = fmaxf(fmaf(z[idx + 16], sc, sh), 0.f);
  float z11 = fmaxf(fmaf(z[idx + 17], sc, sh), 0.f);
  float f = fmaxf(fmaxf(z00, z01), fmaxf(z10, z11));
  __hip_bfloat16 h = __float2bfloat16(f);
  unsigned short hu;
  __builtin_memcpy(&hu, &h, 2);
  hi[i] = hu;
  lo[i] = f2us(f - __bfloat162float(h));
}

// ---------------- FC1 MFMA GEMM: A = int8 codes converted in-register ----------------
DEV bf16x8 i8_to_bf16x8(i8x8 v) {
  us8 u;
#pragma unroll
  for (int j = 0; j < 8; ++j) {
    int c = v[j];
    u[j] = (unsigned short)(c == 0 ? 0 : (c > 0 ? 0x3F80 : 0xBF80));
  }
  bf16x8 r;
  __builtin_memcpy(&r, &u, 16);
  return r;
}

// grid (8 o-blocks, 128 k-slices of 256) = 1024 blocks
__global__ __launch_bounds__(256) void fc1_mfma(const int8_t* __restrict__ c1,
                                                const unsigned short* __restrict__ aHi,
                                                const unsigned short* __restrict__ aLo,
                                                float* __restrict__ partial) {
  const int w = threadIdx.x >> 6, lane = threadIdx.x & 63;
  const int l15 = lane & 15, l4 = lane >> 4;
  const int o0 = blockIdx.x * 128 + w * 32;
  const int s = blockIdx.y;
  const int kbase = s * 256 + l4 * 8;
  f32x4 acc[2][2];
#pragma unroll
  for (int g = 0; g < 2; ++g)
#pragma unroll
    for (int t = 0; t < 2; ++t) acc[g][t] = (f32x4){0.f, 0.f, 0.f, 0.f};
#pragma unroll 2
  for (int kc = 0; kc < 256; kc += 32) {
    bf16x8 a0 = i8_to_bf16x8(*(const i8x8*)(c1 + (size_t)(o0 + l15) * 32768 + kbase + kc));
    bf16x8 a1 = i8_to_bf16x8(*(const i8x8*)(c1 + (size_t)(o0 + 16 + l15) * 32768 + kbase + kc));
    bf16x8 bh0 = *(const bf16x8*)(aHi + (size_t)l15 * 32768 + kbase + kc);
    bf16x8 bl0 = *(const bf16x8*)(aLo + (size_t)l15 * 32768 + kbase + kc);
    bf16x8 bh1 = *(const bf16x8*)(aHi + (size_t)(16 + l15) * 32768 + kbase + kc);
    bf16x8 bl1 = *(const bf16x8*)(aLo + (size_t)(16 + l15) * 32768 + kbase + kc);
    acc[0][0] = __builtin_amdgcn_mfma_f32_16x16x32_bf16(a0, bh0, acc[0][0], 0, 0, 0);
    acc[0][0] = __builtin_amdgcn_mfma_f32_16x16x32_bf16(a0, bl0, acc[0][0], 0, 0, 0);
    acc[1][0] = __builtin_amdgcn_mfma_f32_16x16x32_bf16(a1, bh0, acc[1][0], 0, 0, 0);
    acc[1][0] = __builtin_amdgcn_mfma_f32_16x16x32_bf16(a1, bl0, acc[1][0], 0, 0, 0);
    acc[0][1] = __builtin_amdgcn_mfma_f32_16x16x32_bf16(a0, bh1, acc[0][1], 0, 0, 0);
    acc[0][1] = __builtin_amdgcn_mfma_f32_16x16x32_bf16(a0, bl1, acc[0][1], 0, 0, 0);
    acc[1][1] = __builtin_amdgcn_mfma_f32_16x16x32_bf16(a1, bh1, acc[1][1], 0, 0, 0);
    acc[1][1] = __builtin_amdgcn_mfma_f32_16x16x32_bf16(a1, bl1, acc[1][1], 0, 0, 0);
  }
#pragma unroll
  for (int g = 0; g < 2; ++g)
#pragma unroll
    for (int t = 0; t < 2; ++t)
#pragma unroll
      for (int r = 0; r < 4; ++r) {
        int o = o0 + g * 16 + l4 * 4 + r;
        int n = t * 16 + l15;
        partial[((size_t)s * 1024 + o) * 32 + n] = acc[g][t][r];
      }
}

__global__ __launch_bounds__(256) void fc1_fin(const float* __restrict__ partial,
                                               const double* __restrict__ st,
                                               const float* __restrict__ fb,
                                               float* __restrict__ fc1T) {
  int i = blockIdx.x * 256 + threadIdx.x;  // 32768
  int o = i >> 5;
  float s = 0.f;
#pragma unroll 8
  for (int t = 0; t < 128; ++t) s += partial[(size_t)t * 32768 + i];
  float alpha = tern_alpha_d(st, 33554432.0);
  fc1T[i] = fmaxf(fmaf(s, alpha, fb[o]), 0.f);
}

// ---------------- FC2 (row-parallel; tiny) ----------------
__global__ __launch_bounds__(256) void fc2_kernel(const float* __restrict__ xT,
                                                  const int8_t* __restrict__ codes,
                                                  const double* __restrict__ st,
                                                  const float* __restrict__ fb,
                                                  float* __restrict__ out) {
  const int o = blockIdx.x;
  float acc[32];
#pragma unroll
  for (int j = 0; j < 32; ++j) acc[j] = 0.f;
  const int8_t* crow = codes + (size_t)o * 1024;
  for (int k = threadIdx.x; k < 1024; k += 256) {
    int cv = crow[k];
    if (cv != 0) {
      float c = (float)cv;
      const float4* pv = (const float4*)(xT + ((size_t)k << 5));
#pragma unroll
      for (int j = 0; j < 8; ++j) {
        float4 v = pv[j];
        acc[4 * j + 0] = fmaf(c, v.x, acc[4 * j + 0]);
        acc[4 * j + 1] = fmaf(c, v.y, acc[4 * j + 1]);
        acc[4 * j + 2] = fmaf(c, v.z, acc[4 * j + 2]);
        acc[4 * j + 3] = fmaf(c, v.w, acc[4 * j + 3]);
      }
    }
  }
#pragma unroll
  for (int j = 0; j < 32; ++j) {
#pragma unroll
    for (int off = 32; off > 0; off >>= 1) acc[j] += __shfl_down(acc[j], off);
  }
  __shared__ float red[4][32];
  int lane = threadIdx.x & 63, wv = threadIdx.x >> 6;
  if (lane == 0) {
#pragma unroll
    for (int j = 0; j < 32; ++j) red[wv][j] = acc[j];
  }
  __syncthreads();
  if (threadIdx.x < 32) {
    int n = threadIdx.x;
    float alpha = tern_alpha_d(st, 1024000.0);
    out[(size_t)n * 1000 + o] = (red[0][n] + red[1][n] + red[2][n] + red[3][n]) * alpha + fb[o];
  }
}

// ---------------- host ----------------
extern "C" void kernel_launch(void* const* d_in, const int* in_sizes, int n_in, void* d_out,
                              int out_size, void* d_ws, size_t ws_size, hipStream_t stream) {
  const float* x = (const float*)d_in[0];
  const float* w1 = (const float*)d_in[1];
  const float* g1 = (const float*)d_in[3];
  const float* be1 = (const float*)d_in[4];
  const float* w2 = (const float*)d_in[5];
  const float* g2 = (const float*)d_in[7];
  const float* be2 = (const float*)d_in[8];
  const float* w3 = (const float*)d_in[9];
  const float* g3 = (const float*)d_in[11];
  const float* be3 = (const float*)d_in[12];
  const float* w4 = (const float*)d_in[13];
  const float* g4 = (const float*)d_in[15];
  const float* be4 = (const float*)d_in[16];
  const float* fw1 = (const float*)d_in[17];
  const float* fb1 = (const float*)d_in[18];
  const float* fw2 = (const float*)d_in[19];
  const float* fb2 = (const float*)d_in[20];
  // b1..b4 cancel exactly under training-mode BN (alpha-folded finalize).
  (void)in_sizes; (void)n_in; (void)out_size; (void)ws_size;

  char* ws = (char*)d_ws;
  size_t off = 0;
  auto alloc = [&](size_t bytes) {
    size_t o = off;
    off += (bytes + 255) & ~(size_t)255;
    return o;
  };
  unsigned short* wb1 = (unsigned short*)(ws + alloc((size_t)2048 * 2));     // [64][32] im2col-27
  unsigned short* wb2 = (unsigned short*)(ws + alloc((size_t)73728 * 2));    // [128][576]
  unsigned short* wb3 = (unsigned short*)(ws + alloc((size_t)294912 * 2));   // [256][1152]
  unsigned short* wb4 = (unsigned short*)(ws + alloc((size_t)1179648 * 2));  // [512][2304]
  int8_t* c1 = (int8_t*)(ws + alloc((size_t)33554432));  // fc1 int8 codes [1024][32768]
  int8_t* c2 = (int8_t*)(ws + alloc((size_t)1024000));
  double* dst = (double*)(ws + alloc((size_t)(32 + 3 * 384) * 8));
  double* absB = dst + 32;
  double* msB = absB + 384;
  double* cntB = msB + 384;
  float* scsh = (float*)(ws + alloc((size_t)4096 * 4));
  double* pS = (double*)(ws + alloc((size_t)262144 * 8));  // max: L1 4096p x 64c
  double* pQ = (double*)(ws + alloc((size_t)262144 * 8));
  float* bufY = (float*)(ws + alloc((size_t)16777216 * 4));  // 67MB: z / fc1part
  float* bufA = (float*)(ws + alloc((size_t)8388608 * 4));   // 33.5MB: pooled NHWC
  unsigned short* actHi = (unsigned short*)(ws + alloc((size_t)1048576 * 2));
  unsigned short* actLo = (unsigned short*)(ws + alloc((size_t)1048576 * 2));
  float* fc1T = (float*)(ws + alloc((size_t)32768 * 4));  // [1024][32]
  float* fc1part = bufY;  // [128][1024][32] = 16.8 MB; bufY dead by FC time

  hipMemsetAsync(dst, 0, (32 + 3 * 384) * 8, stream);

  // ternarize stats: flat proportional grid (exact-fit block ranges).
  TDescs ta;
  ta.d[0] = {fw1, 33554432, 0, 8192, 4};
  ta.d[1] = {w4, 1179648, 8192, 288, 3};
  ta.d[2] = {fw2, 1024000, 8480, 250, 5};
  ta.d[3] = {w3, 294912, 8730, 72, 2};
  ta.d[4] = {w2, 73728, 8802, 18, 1};
  ta.d[5] = {w1, 1728, 8820, 1, 0};
  tern_abs_all<<<8821, 256, 0, stream>>>(ta, absB);
  MDescs tm;
  tm.d[0] = {fw1, c1, 33554432, 0, 8192, 4};
  tm.d[1] = {w4, nullptr, 1179648, 8192, 288, 3};
  tm.d[2] = {fw2, c2, 1024000, 8480, 250, 5};
  tm.d[3] = {w3, nullptr, 294912, 8730, 72, 2};
  tm.d[4] = {w2, nullptr, 73728, 8802, 18, 1};
  tm.d[5] = {w1, nullptr, 1728, 8820, 1, 0};
  tern_masked_code_all<<<8821, 256, 0, stream>>>(tm, absB, msB, cntB);
  tern_collapse<<<6, 64, 0, stream>>>(absB, msB, cntB, dst);
  tern_write_convb_pad<<<8, 256, 0, stream>>>(w1, absB + 0 * 64, wb1);
  tern_write_convb<<<288, 256, 0, stream>>>(w2, absB + 1 * 64, 73728, 64, wb2);
  tern_write_convb<<<1152, 256, 0, stream>>>(w3, absB + 2 * 64, 294912, 128, wb3);
  tern_write_convb<<<4608, 256, 0, stream>>>(w4, absB + 3 * 64, 1179648, 256, wb4);

  float* ss1 = scsh;
  float* ss2 = scsh + 128;
  float* ss3 = scsh + 512;
  float* ss4 = scsh + 1024;

  // Layer 1 (im2col-27, reads x NCHW directly), two-pass recompute; pooled1 -> NHWC bufA.
  conv1_mfma_stats<<<dim3(128, 1, 32), 128, 0, stream>>>(x, wb1, pS, pQ);
  bn_fin_alpha<<<64, 256, 0, stream>>>(pS, pQ, 4096, g1, be1, 524288.0, dst + 0, 1728.0, ss1,
                                       64);
  conv1_mfma_pool<<<dim3(128, 1, 32), 128, 0, stream>>>(x, wb1, ss1, bufA);

  // Layer 2: 64->128 @64x64 (reads pooled1 NHWC in bufA; z -> bufY)
  conv_mfma<64, 64, 8><<<dim3(32, 1, 32), 256, 0, stream>>>(bufA, wb2, bufY, 128, pS, pQ);
  bn_fin_alpha<<<128, 256, 0, stream>>>(pS, pQ, 1024, g2, be2, 131072.0, dst + 4, 73728.0, ss2,
                                        128);
  bn_pool_nhwc<<<dim3(2, 16, 32), 256, 0, stream>>>(bufY, ss2, 128, 5, bufA);

  // Layer 3: 128->256 @32x32
  conv_mfma<128, 32, 4><<<dim3(16, 2, 32), 256, 0, stream>>>(bufA, wb3, bufY, 256, pS, pQ);
  bn_fin_alpha<<<256, 256, 0, stream>>>(pS, pQ, 512, g3, be3, 32768.0, dst + 8, 294912.0, ss3,
                                        256);
  bn_pool_nhwc<<<dim3(4, 4, 32), 256, 0, stream>>>(bufY, ss3, 256, 4, bufA);

  // Layer 4: 256->512 @16x16; fused BN+pool+hilo writes actHi/actLo directly
  conv_mfma<256, 16, 2><<<dim3(8, 4, 32), 256, 0, stream>>>(bufA, wb4, bufY, 512, pS, pQ);
  bn_fin_alpha<<<512, 256, 0, stream>>>(pS, pQ, 256, g4, be4, 8192.0, dst + 12, 1179648.0, ss4,
                                        512);
  bn_pool_hilo<<<4096, 256, 0, stream>>>(bufY, ss4, actHi, actLo);

  // FC1 (int8 codes -> in-register bf16), 1024 blocks; then finalize + FC2
  fc1_mfma<<<dim3(8, 128), 256, 0, stream>>>(c1, actHi, actLo, fc1part);
  fc1_fin<<<128, 256, 0, stream>>>(fc1part, dst + 16, fb1, fc1T);
  fc2_kernel<<<1000, 256, 0, stream>>>(fc1T, c2, dst + 20, fb2, (float*)d_out);
}

// Round 8
// 565.113 us; speedup vs baseline: 1.5728x; 1.0745x over previous
//
#include <hip/hip_runtime.h>
#include <hip/hip_bf16.h>
#include <stdint.h>

#define DEV __device__ __forceinline__

typedef __bf16 bf16x8 __attribute__((ext_vector_type(8)));
typedef float f32x4 __attribute__((ext_vector_type(4)));
typedef unsigned short us8 __attribute__((ext_vector_type(8)));
typedef int8_t i8x8 __attribute__((ext_vector_type(8)));

DEV unsigned short f2us(float f) {
  __hip_bfloat16 h = __float2bfloat16(f);
  unsigned short u;
  __builtin_memcpy(&u, &h, 2);
  return u;
}

DEV double wave_reduce_d(double v) {
#pragma unroll
  for (int off = 32; off > 0; off >>= 1) v += __shfl_down(v, off);
  return v;
}

DEV double dbl_block_reduce(double v, double* lds) {
  v = wave_reduce_d(v);
  int lane = threadIdx.x & 63, w = threadIdx.x >> 6;
  if (lane == 0) lds[w] = v;
  __syncthreads();
  double r = 0.0;
  if (threadIdx.x == 0) r = lds[0] + lds[1] + lds[2] + lds[3];
  __syncthreads();
  return r;
}

// ---------------- ternarize: fp64 stats, flat proportional grid ----------------
struct TDesc { const float* w; int n; int b0; int nb; int slot; };
struct TDescs { TDesc d[6]; };

DEV double abs4d(float4 v) {
  return fabs((double)v.x) + fabs((double)v.y) + fabs((double)v.z) + fabs((double)v.w);
}

DEV double bucket_sum64(const double* b) {
  double s = 0.0;
#pragma unroll
  for (int j = 0; j < 64; ++j) s += b[j];
  return s;
}

__global__ __launch_bounds__(256) void tern_abs_all(TDescs td, double* __restrict__ absB) {
  __shared__ double lds[4];
  const int b = blockIdx.x;
  int k = 0;
  while (k < 5 && b >= td.d[k + 1].b0) ++k;  // d[] sorted ascending by b0
  const TDesc D = td.d[k];
  const float4* w4 = (const float4*)D.w;
  const int n4 = D.n >> 2;
  const int S = D.nb * 256;
  int i = (b - D.b0) * 256 + threadIdx.x;
  double s0 = 0.0, s1 = 0.0, s2 = 0.0, s3 = 0.0;
  for (; i + 3 * S < n4; i += 4 * S) {
    float4 v0 = w4[i];
    float4 v1 = w4[i + S];
    float4 v2 = w4[i + 2 * S];
    float4 v3 = w4[i + 3 * S];
    s0 += abs4d(v0);
    s1 += abs4d(v1);
    s2 += abs4d(v2);
    s3 += abs4d(v3);
  }
  for (; i < n4; i += S) s0 += abs4d(w4[i]);
  double s = (s0 + s1) + (s2 + s3);
  s = dbl_block_reduce(s, lds);
  if (threadIdx.x == 0 && s != 0.0) atomicAdd(absB + D.slot * 64 + (b & 63), s);
}

struct MDesc { const float* w; int8_t* out; int n; int b0; int nb; int slot; };
struct MDescs { MDesc d[6]; };

DEV int proc4(float4 v, double delta, double& ms, int& cnt) {
  float e[4] = {v.x, v.y, v.z, v.w};
  char pk[4];
#pragma unroll
  for (int j = 0; j < 4; ++j) {
    double d = (double)e[j];
    double a = fabs(d);
    if (a > delta) { ms += a; cnt += 1; }
    pk[j] = (char)((d > delta) ? 1 : ((d < -delta) ? -1 : 0));
  }
  int w32;
  __builtin_memcpy(&w32, pk, 4);
  return w32;
}

__global__ __launch_bounds__(256) void tern_masked_code_all(MDescs td,
                                                            const double* __restrict__ absB,
                                                            double* __restrict__ msB,
                                                            double* __restrict__ cntB) {
  __shared__ double lds[4];
  const int b = blockIdx.x;
  int k = 0;
  while (k < 5 && b >= td.d[k + 1].b0) ++k;
  const MDesc D = td.d[k];
  const float4* w4 = (const float4*)D.w;
  int8_t* out = D.out;
  const int n4 = D.n >> 2;
  const double delta = 0.7 * bucket_sum64(absB + D.slot * 64) / (double)D.n;
  const int S = D.nb * 256;
  int i = (b - D.b0) * 256 + threadIdx.x;
  double m0 = 0.0, m1 = 0.0, m2 = 0.0, m3 = 0.0;
  int c0 = 0, c1x = 0, c2x = 0, c3 = 0;
  for (; i + 3 * S < n4; i += 4 * S) {
    float4 v0 = w4[i];
    float4 v1 = w4[i + S];
    float4 v2 = w4[i + 2 * S];
    float4 v3 = w4[i + 3 * S];
    int p0 = proc4(v0, delta, m0, c0);
    int p1 = proc4(v1, delta, m1, c1x);
    int p2 = proc4(v2, delta, m2, c2x);
    int p3 = proc4(v3, delta, m3, c3);
    if (out) {
      *(int*)(out + ((size_t)i << 2)) = p0;
      *(int*)(out + ((size_t)(i + S) << 2)) = p1;
      *(int*)(out + ((size_t)(i + 2 * S) << 2)) = p2;
      *(int*)(out + ((size_t)(i + 3 * S) << 2)) = p3;
    }
  }
  for (; i < n4; i += S) {
    int p = proc4(w4[i], delta, m0, c0);
    if (out) *(int*)(out + ((size_t)i << 2)) = p;
  }
  double ms = (m0 + m1) + (m2 + m3);
  double cnt = (double)(c0 + c1x + c2x + c3);
  ms = dbl_block_reduce(ms, lds);
  cnt = dbl_block_reduce(cnt, lds);
  if (threadIdx.x == 0 && cnt != 0.0) {
    atomicAdd(msB + D.slot * 64 + (b & 63), ms);
    atomicAdd(cntB + D.slot * 64 + (b & 63), cnt);
  }
}

__global__ __launch_bounds__(64) void tern_collapse(const double* __restrict__ absB,
                                                    const double* __restrict__ msB,
                                                    const double* __restrict__ cntB,
                                                    double* __restrict__ st) {
  const int t = blockIdx.x;
  const int lane = threadIdx.x;
  double a = absB[t * 64 + lane];
  double m = msB[t * 64 + lane];
  double c = cntB[t * 64 + lane];
#pragma unroll
  for (int off = 32; off > 0; off >>= 1) {
    a += __shfl_down(a, off);
    m += __shfl_down(m, off);
    c += __shfl_down(c, off);
  }
  if (lane == 0) {
    st[t * 4] = a;
    st[t * 4 + 1] = m;
    st[t * 4 + 2] = c;
  }
}

DEV float tern_alpha_d(const double* st, double n) {
  double cnt = st[2];
  return (float)(cnt > 0.0 ? st[1] / fmax(cnt, 1.0) : st[0] / n);
}
DEV double tern_alpha_dd(const double* st, double n) {
  double cnt = st[2];
  return cnt > 0.0 ? st[1] / fmax(cnt, 1.0) : st[0] / n;
}

// conv2-4 weights -> bf16 codes {-1,0,+1}, PACKED per-wave-load layout:
// wbP[blk128][cc][tap][wave][g][lane*8+j] so each MFMA A-fragment load is one
// contiguous 1KB (was 16 scattered 64B lines at co*K stride).
// co = blk*128 + wave*32 + g*16 + l15; k = cc*32 + l4*8 + j; lane = l4*16+l15.
__global__ __launch_bounds__(256) void tern_write_convb(const float* __restrict__ w,
                                                        const double* __restrict__ ab, int total,
                                                        int CIN, unsigned short* __restrict__ out) {
  int i = blockIdx.x * 256 + threadIdx.x;
  if (i >= total) return;
  double delta = 0.7 * bucket_sum64(ab) / (double)total;
  double v = (double)w[i];
  float code = v > delta ? 1.f : (v < -delta ? -1.f : 0.f);
  int cin9 = CIN * 9;
  int o = i / cin9, rem = i - o * cin9;
  int ci = rem / 9, tap = rem - ci * 9;
  int CH = CIN >> 5;
  int blk = o >> 7, cop = o & 127;
  int wv = cop >> 5, g = (cop >> 4) & 1, l15 = cop & 15;
  int cc = ci >> 5, l4 = (ci >> 3) & 3, j = ci & 7;
  size_t idx =
      (((((size_t)(blk * CH + cc) * 9 + tap) * 4 + wv) * 2 + g) * 64 + l4 * 16 + l15) * 8 + j;
  out[idx] = f2us(code);
}

// conv1 weights: im2col-27 layout [64 cout][k=dy*9+dx*3+ci, pad 27..31 = 0]
__global__ __launch_bounds__(256) void tern_write_convb_pad(const float* __restrict__ w,
                                                            const double* __restrict__ ab,
                                                            unsigned short* __restrict__ out) {
  int i = blockIdx.x * 256 + threadIdx.x;
  if (i >= 64 * 32) return;
  int o = i >> 5, k = i & 31;
  float code = 0.f;
  if (k < 27) {
    int dy = k / 9, r = k - dy * 9, dx = r / 3, ci = r - dx * 3;
    int tap = dy * 3 + dx;
    double delta = 0.7 * bucket_sum64(ab) / 1728.0;
    double v = (double)w[(o * 3 + ci) * 9 + tap];
    code = v > delta ? 1.f : (v < -delta ? -1.f : 0.f);
  }
  out[i] = f2us(code);
}

// ---------------- BN finalize (alpha-folded; bias cancels exactly) ----------------
// pS/pQ layout [p][co] (coalesced writes from conv)
__global__ __launch_bounds__(256) void bn_fin_alpha(const double* __restrict__ pS,
                                                    const double* __restrict__ pQ, int P,
                                                    const float* __restrict__ g,
                                                    const float* __restrict__ be, double M,
                                                    const double* __restrict__ st, double nels,
                                                    float* __restrict__ scsh, int C) {
  __shared__ double lds[4];
  const int c = blockIdx.x;
  double s = 0.0, q = 0.0;
  for (int p = threadIdx.x; p < P; p += 256) {
    s += pS[(size_t)p * C + c];
    q += pQ[(size_t)p * C + c];
  }
  s = dbl_block_reduce(s, lds);
  q = dbl_block_reduce(q, lds);
  if (threadIdx.x == 0) {
    double al = tern_alpha_dd(st, nels);
    double mean = s / M;
    double var = q / M - mean * mean;
    double sc = (double)g[c] * al / sqrt(al * al * var + 1e-5);
    scsh[c] = (float)sc;
    scsh[C + c] = (float)((double)be[c] - mean * sc);
  }
}

// ---------------- hi/lo bf16 split helper ----------------
DEV void cvt8(float4 a, float4 b, us8& hv, us8& lv) {
  float f[8] = {a.x, a.y, a.z, a.w, b.x, b.y, b.z, b.w};
#pragma unroll
  for (int e = 0; e < 8; ++e) {
    __hip_bfloat16 h = __float2bfloat16(f[e]);
    unsigned short hu;
    __builtin_memcpy(&hu, &h, 2);
    hv[e] = hu;
    lv[e] = f2us(f[e] - __bfloat162float(h));
  }
}

// fused fp64 BN partial write (per wave, 16-lane reduce), layout [p][co]
template <int PH>
DEV void bn_partials(const f32x4 (&acc)[2][PH], int wvCout, int CO, int p,
                     double* __restrict__ pS, double* __restrict__ pQ) {
  const int lane = threadIdx.x & 63;
  const int l15 = lane & 15, l4 = lane >> 4;
#pragma unroll
  for (int g = 0; g < 2; ++g) {
    float sv[4] = {0, 0, 0, 0}, qv[4] = {0, 0, 0, 0};
#pragma unroll
    for (int pt = 0; pt < PH; ++pt)
#pragma unroll
      for (int r = 0; r < 4; ++r) {
        float v = acc[g][pt][r];
        sv[r] += v;
        qv[r] = fmaf(v, v, qv[r]);
      }
#pragma unroll
    for (int r = 0; r < 4; ++r)
#pragma unroll
      for (int m = 1; m < 16; m <<= 1) {
        sv[r] += __shfl_xor(sv[r], m);
        qv[r] += __shfl_xor(qv[r], m);
      }
    if (l15 == 0) {
#pragma unroll
      for (int r = 0; r < 4; ++r) {
        int co = wvCout + g * 16 + l4 * 4 + r;
        pS[(size_t)p * CO + co] = (double)sv[r];
        pQ[(size_t)p * CO + co] = (double)qv[r];
      }
    }
  }
}

// ---------------- MFMA tap loop (layers 2-4, packed weights) ----------------
template <int CIN, int PH>
DEV void mfma_phase(const unsigned short* __restrict__ wT, const unsigned short* hC,
                    const unsigned short* lC, int wv, int blk, int cc, int lane,
                    f32x4 (&acc)[2][PH]) {
  constexpr int CH = CIN / 32;
  const int l15 = lane & 15, l4 = lane >> 4;
#pragma unroll
  for (int tap = 0; tap < 9; ++tap) {
    const int dy = tap / 3, dx = tap % 3;
    bf16x8 aF[2];
    const size_t wbase = (((size_t)(blk * CH + cc) * 9 + tap) * 4 + wv) * 2;
#pragma unroll
    for (int g = 0; g < 2; ++g)
      aF[g] = *(const bf16x8*)(wT + (wbase + g) * 512 + lane * 8);
    const int tb = (dy * 18 + dx + l15) * 32 + l4 * 8;
#pragma unroll
    for (int pt = 0; pt < PH; ++pt) {
      int off = tb + pt * (18 * 32);
      bf16x8 bh = *(const bf16x8*)(hC + off);
      bf16x8 bl = *(const bf16x8*)(lC + off);
      acc[0][pt] = __builtin_amdgcn_mfma_f32_16x16x32_bf16(aF[0], bh, acc[0][pt], 0, 0, 0);
      acc[1][pt] = __builtin_amdgcn_mfma_f32_16x16x32_bf16(aF[1], bh, acc[1][pt], 0, 0, 0);
      acc[0][pt] = __builtin_amdgcn_mfma_f32_16x16x32_bf16(aF[0], bl, acc[0][pt], 0, 0, 0);
      acc[1][pt] = __builtin_amdgcn_mfma_f32_16x16x32_bf16(aF[1], bl, acc[1][pt], 0, 0, 0);
    }
  }
}

// layers 2-4: R1 geometry (4-wave, PH=8/4/2, single-buffer LDS) + register
// prefetch under a 2-barrier/chunk discipline.  z store (NCHW) + BN partials.
template <int CIN, int H, int PH>
__global__ __launch_bounds__(256) void conv_mfma(const float* __restrict__ inNHWC,
                                                 const unsigned short* __restrict__ wT,
                                                 float* __restrict__ z, int COUT,
                                                 double* __restrict__ pS,
                                                 double* __restrict__ pQ) {
  constexpr int W = H;
  constexpr int CH = CIN / 32;
  constexpr int TX = W / 16;
  constexpr int NU = (PH + 2) * 18 * 4;
  constexpr int T = 256;
  constexpr int UPT = (NU + T - 1) / T;
  constexpr int TILE = (PH + 2) * 18 * 32;
  __shared__ unsigned short hiT[TILE];
  __shared__ unsigned short loT[TILE];
  const int bx = blockIdx.x;
  const int tX = bx % TX, tY = bx / TX;
  const int n = blockIdx.z;
  const int wave = threadIdx.x >> 6, lane = threadIdx.x & 63;
  const int l15 = lane & 15, l4 = lane >> 4;
  const int wvCout = blockIdx.y * 128 + wave * 32;
  const int x0 = tX * 16, y0 = tY * PH;

  f32x4 acc[2][PH];
#pragma unroll
  for (int g = 0; g < 2; ++g)
#pragma unroll
    for (int pt = 0; pt < PH; ++pt) acc[g][pt] = (f32x4){0.f, 0.f, 0.f, 0.f};

  // cc-independent staging descriptors
  const float* srcB[UPT];
  int ldsO[UPT];
  bool inb[UPT];
#pragma unroll
  for (int j = 0; j < UPT; ++j) {
    int u = threadIdx.x + j * T;
    int q = u & 3, rem = u >> 2;
    int xx = rem % 18, yy = rem / 18;
    int gy = y0 + yy - 1, gx = x0 + xx - 1;
    bool ok = (u < NU) && ((unsigned)gy < (unsigned)H) && ((unsigned)gx < (unsigned)W);
    inb[j] = ok;
    int cy = ok ? gy : 0, cx = ok ? gx : 0;
    srcB[j] = inNHWC + (((size_t)(n * H + cy) * W + cx) * CIN + q * 8);
    ldsO[j] = (rem << 5) + (q << 3);
  }
  float4 pa[UPT], pb[UPT];
#pragma unroll
  for (int j = 0; j < UPT; ++j)
    if (inb[j]) {
      pa[j] = *(const float4*)srcB[j];
      pb[j] = *(const float4*)(srcB[j] + 4);
    }
#pragma unroll 1
  for (int cc = 0; cc < CH; ++cc) {
    if (cc) {  // all waves done reading LDS of chunk cc-1
      asm volatile("s_waitcnt lgkmcnt(0)" ::: "memory");
      __builtin_amdgcn_s_barrier();
      __builtin_amdgcn_sched_barrier(0);
    }
#pragma unroll
    for (int j = 0; j < UPT; ++j) {
      int u = threadIdx.x + j * T;
      if (u < NU) {
        us8 hv = (us8)0, lv = (us8)0;
        if (inb[j]) cvt8(pa[j], pb[j], hv, lv);
        *(us8*)(hiT + ldsO[j]) = hv;
        *(us8*)(loT + ldsO[j]) = lv;
      }
    }
    asm volatile("s_waitcnt lgkmcnt(0)" ::: "memory");
    __builtin_amdgcn_s_barrier();
    __builtin_amdgcn_sched_barrier(0);
    // prefetch next chunk's globals; they fly under the MFMA phase (T14)
    if (cc + 1 < CH) {
#pragma unroll
      for (int j = 0; j < UPT; ++j)
        if (inb[j]) {
          pa[j] = *(const float4*)(srcB[j] + (size_t)(cc + 1) * 32);
          pb[j] = *(const float4*)(srcB[j] + (size_t)(cc + 1) * 32 + 4);
        }
    }
    mfma_phase<CIN, PH>(wT, hiT, loT, wave, blockIdx.y, cc, lane, acc);
  }

#pragma unroll
  for (int g = 0; g < 2; ++g)
#pragma unroll
    for (int pt = 0; pt < PH; ++pt) {
      int oy = y0 + pt;
#pragma unroll
      for (int r = 0; r < 4; ++r) {
        int co = wvCout + g * 16 + l4 * 4 + r;
        z[(((size_t)n * COUT + co) * H + oy) * W + x0 + l15] = acc[g][pt][r];
      }
    }
  bn_partials<PH>(acc, wvCout, COUT, n * gridDim.x + bx, pS, pQ);
}

// ---------------- conv1: im2col-27 (3ch x 9taps packed into one K=32 slice) ----------
DEV void conv1_core(const float* __restrict__ x, const unsigned short* __restrict__ wb,
                    int n, int x0, int y0, float* xt, f32x4 (&acc)[2][8]) {
  const int lane = threadIdx.x & 63;
  const int l15 = lane & 15, l4 = lane >> 4;
  const int wvCout = (threadIdx.x >> 6) * 32;
#pragma unroll
  for (int g = 0; g < 2; ++g)
#pragma unroll
    for (int pt = 0; pt < 8; ++pt) acc[g][pt] = (f32x4){0.f, 0.f, 0.f, 0.f};

  for (int u = threadIdx.x; u < 540; u += 128) {  // (8+2) rows x 18 x 3ch
    int yy = u / 54, rem = u - yy * 54;
    int tx = rem / 3, ci = rem - tx * 3;
    int gy = y0 + yy - 1, gx = x0 + tx - 1;
    float v = 0.f;
    if ((unsigned)gy < 128u && (unsigned)gx < 128u)
      v = x[(((size_t)n * 3 + ci) << 14) + (gy << 7) + gx];
    xt[u] = v;
  }
  asm volatile("s_waitcnt lgkmcnt(0)" ::: "memory");
  __builtin_amdgcn_s_barrier();
  __builtin_amdgcn_sched_barrier(0);

  bf16x8 aW[2];
#pragma unroll
  for (int g = 0; g < 2; ++g)
    aW[g] = *(const bf16x8*)(wb + (size_t)(wvCout + g * 16 + l15) * 32 + l4 * 8);

#pragma unroll
  for (int pt = 0; pt < 8; ++pt) {
    us8 hv = (us8)0, lv = (us8)0;
#pragma unroll
    for (int j = 0; j < 8; ++j) {
      int k = l4 * 8 + j;
      float v = 0.f;
      if (k < 27) {
        int dy = k / 9;
        int r = k - dy * 9;
        v = xt[(pt + dy) * 54 + l15 * 3 + r];
      }
      __hip_bfloat16 h = __float2bfloat16(v);
      unsigned short hu;
      __builtin_memcpy(&hu, &h, 2);
      hv[j] = hu;
      lv[j] = f2us(v - __bfloat162float(h));
    }
    bf16x8 bh, bl;
    __builtin_memcpy(&bh, &hv, 16);
    __builtin_memcpy(&bl, &lv, 16);
    acc[0][pt] = __builtin_amdgcn_mfma_f32_16x16x32_bf16(aW[0], bh, acc[0][pt], 0, 0, 0);
    acc[0][pt] = __builtin_amdgcn_mfma_f32_16x16x32_bf16(aW[0], bl, acc[0][pt], 0, 0, 0);
    acc[1][pt] = __builtin_amdgcn_mfma_f32_16x16x32_bf16(aW[1], bh, acc[1][pt], 0, 0, 0);
    acc[1][pt] = __builtin_amdgcn_mfma_f32_16x16x32_bf16(aW[1], bl, acc[1][pt], 0, 0, 0);
  }
}

// layer 1 pass 1: partials only (z never materialized)
__global__ __launch_bounds__(128) void conv1_mfma_stats(const float* __restrict__ x,
                                                        const unsigned short* __restrict__ wT,
                                                        double* __restrict__ pS,
                                                        double* __restrict__ pQ) {
  __shared__ float xt[540];
  const int bx = blockIdx.x;
  const int tX = bx & 7, tY = bx >> 3;
  const int n = blockIdx.z;
  f32x4 acc[2][8];
  conv1_core(x, wT, n, tX * 16, tY * 8, xt, acc);
  bn_partials<8>(acc, (threadIdx.x >> 6) * 32, 64, n * gridDim.x + bx, pS, pQ);
}

// layer 1 pass 2: recompute, BN+relu+2x2 maxpool, write pooled NHWC directly
__global__ __launch_bounds__(128) void conv1_mfma_pool(const float* __restrict__ x,
                                                       const unsigned short* __restrict__ wT,
                                                       const float* __restrict__ scsh,
                                                       float* __restrict__ outNHWC) {
  __shared__ float xt[540];
  const int bx = blockIdx.x;
  const int tX = bx & 7, tY = bx >> 3;
  const int n = blockIdx.z;
  const int lane = threadIdx.x & 63;
  const int l15 = lane & 15, l4 = lane >> 4;
  const int wvCout = (threadIdx.x >> 6) * 32;
  const int x0 = tX * 16, y0 = tY * 8;
  f32x4 acc[2][8];
  conv1_core(x, wT, n, x0, y0, xt, acc);
#pragma unroll
  for (int g = 0; g < 2; ++g) {
    const int co0 = wvCout + g * 16 + l4 * 4;
#pragma unroll
    for (int pt = 0; pt < 8; pt += 2) {
      float m[4];
#pragma unroll
      for (int r = 0; r < 4; ++r) {
        float sc = scsh[co0 + r], sh = scsh[64 + co0 + r];
        float v0 = fmaxf(fmaf(acc[g][pt][r], sc, sh), 0.f);
        float v1 = fmaxf(fmaf(acc[g][pt + 1][r], sc, sh), 0.f);
        float a = fmaxf(v0, v1);
        m[r] = fmaxf(a, __shfl_xor(a, 1));
      }
      if ((l15 & 1) == 0) {
        int oy = (y0 + pt) >> 1, ox = (x0 + l15) >> 1;
        *(float4*)(outNHWC + ((((size_t)n * 64 + oy) * 64 + ox) << 6) + co0) =
            make_float4(m[0], m[1], m[2], m[3]);
      }
    }
  }
}

// ---------------- fused BN+relu+pool + NCHW->NHWC transpose (L2/L3) ----------------
__global__ __launch_bounds__(256) void bn_pool_nhwc(const float* __restrict__ z,
                                                    const float* __restrict__ scsh, int C,
                                                    int lw, float* __restrict__ out) {
  __shared__ float t[64][65];
  const int Wo = 1 << lw, Wi = Wo << 1;
  const int c0 = blockIdx.x * 64, p0 = blockIdx.y * 64, n = blockIdx.z;
  const int NP = Wo * Wo;
  for (int u = threadIdx.x; u < 4096; u += 256) {
    int cl = u >> 6, pl = u & 63;
    int pp = p0 + pl, ho = pp >> lw, wo = pp & (Wo - 1);
    int c = c0 + cl;
    size_t idx = ((size_t)(n * C + c) * Wi + (ho << 1)) * Wi + (wo << 1);
    float sc = scsh[c], sh = scsh[C + c];
    float z00 = fmaxf(fmaf(z[idx], sc, sh), 0.f);
    float z01 = fmaxf(fmaf(z[idx + 1], sc, sh), 0.f);
    float z10 = fmaxf(fmaf(z[idx + Wi], sc, sh), 0.f);
    float z11 = fmaxf(fmaf(z[idx + Wi + 1], sc, sh), 0.f);
    t[cl][pl] = fmaxf(fmaxf(z00, z01), fmaxf(z10, z11));
  }
  __syncthreads();
  for (int u = threadIdx.x; u < 4096; u += 256) {
    int pl = u >> 6, cl = u & 63;
    out[((size_t)n * NP + p0 + pl) * C + c0 + cl] = t[cl][pl];
  }
}

// ---------------- L4: fused BN+relu+pool + hi/lo split (NCHW flat out) ----------------
__global__ __launch_bounds__(256) void bn_pool_hilo(const float* __restrict__ z,
                                                    const float* __restrict__ scsh,
                                                    unsigned short* __restrict__ hi,
                                                    unsigned short* __restrict__ lo) {
  int i = blockIdx.x * 256 + threadIdx.x;  // 32*512*8*8 = 1048576
  int wo = i & 7, ho = (i >> 3) & 7, c = (i >> 6) & 511, n = i >> 15;
  float sc = scsh[c], sh = scsh[512 + c];
  size_t idx = ((size_t)(n * 512 + c) * 16 + (ho << 1)) * 16 + (wo << 1);
  float z00 = fmaxf(fmaf(z[idx], sc, sh), 0.f);
  float z01 = fmaxf(fmaf(z[idx + 1], sc, sh), 0.f);
  float z10 = fmaxf(fmaf(z[idx + 16], sc, sh), 0.f);
  float z11 = fmaxf(fmaf(z[idx + 17], sc, sh), 0.f);
  float f = fmaxf(fmaxf(z00, z01), fmaxf(z10, z11));
  __hip_bfloat16 h = __float2bfloat16(f);
  unsigned short hu;
  __builtin_memcpy(&hu, &h, 2);
  hi[i] = hu;
  lo[i] = f2us(f - __bfloat162float(h));
}

// ---------------- FC1 MFMA GEMM: A = int8 codes converted in-register ----------------
DEV bf16x8 i8_to_bf16x8(i8x8 v) {
  us8 u;
#pragma unroll
  for (int j = 0; j < 8; ++j) {
    int c = v[j];
    u[j] = (unsigned short)(c == 0 ? 0 : (c > 0 ? 0x3F80 : 0xBF80));
  }
  bf16x8 r;
  __builtin_memcpy(&r, &u, 16);
  return r;
}

// grid (8 o-blocks, 128 k-slices of 256) = 1024 blocks
__global__ __launch_bounds__(256) void fc1_mfma(const int8_t* __restrict__ c1,
                                                const unsigned short* __restrict__ aHi,
                                                const unsigned short* __restrict__ aLo,
                                                float* __restrict__ partial) {
  const int w = threadIdx.x >> 6, lane = threadIdx.x & 63;
  const int l15 = lane & 15, l4 = lane >> 4;
  const int o0 = blockIdx.x * 128 + w * 32;
  const int s = blockIdx.y;
  const int kbase = s * 256 + l4 * 8;
  f32x4 acc[2][2];
#pragma unroll
  for (int g = 0; g < 2; ++g)
#pragma unroll
    for (int t = 0; t < 2; ++t) acc[g][t] = (f32x4){0.f, 0.f, 0.f, 0.f};
#pragma unroll 2
  for (int kc = 0; kc < 256; kc += 32) {
    bf16x8 a0 = i8_to_bf16x8(*(const i8x8*)(c1 + (size_t)(o0 + l15) * 32768 + kbase + kc));
    bf16x8 a1 = i8_to_bf16x8(*(const i8x8*)(c1 + (size_t)(o0 + 16 + l15) * 32768 + kbase + kc));
    bf16x8 bh0 = *(const bf16x8*)(aHi + (size_t)l15 * 32768 + kbase + kc);
    bf16x8 bl0 = *(const bf16x8*)(aLo + (size_t)l15 * 32768 + kbase + kc);
    bf16x8 bh1 = *(const bf16x8*)(aHi + (size_t)(16 + l15) * 32768 + kbase + kc);
    bf16x8 bl1 = *(const bf16x8*)(aLo + (size_t)(16 + l15) * 32768 + kbase + kc);
    acc[0][0] = __builtin_amdgcn_mfma_f32_16x16x32_bf16(a0, bh0, acc[0][0], 0, 0, 0);
    acc[0][0] = __builtin_amdgcn_mfma_f32_16x16x32_bf16(a0, bl0, acc[0][0], 0, 0, 0);
    acc[1][0] = __builtin_amdgcn_mfma_f32_16x16x32_bf16(a1, bh0, acc[1][0], 0, 0, 0);
    acc[1][0] = __builtin_amdgcn_mfma_f32_16x16x32_bf16(a1, bl0, acc[1][0], 0, 0, 0);
    acc[0][1] = __builtin_amdgcn_mfma_f32_16x16x32_bf16(a0, bh1, acc[0][1], 0, 0, 0);
    acc[0][1] = __builtin_amdgcn_mfma_f32_16x16x32_bf16(a0, bl1, acc[0][1], 0, 0, 0);
    acc[1][1] = __builtin_amdgcn_mfma_f32_16x16x32_bf16(a1, bh1, acc[1][1], 0, 0, 0);
    acc[1][1] = __builtin_amdgcn_mfma_f32_16x16x32_bf16(a1, bl1, acc[1][1], 0, 0, 0);
  }
#pragma unroll
  for (int g = 0; g < 2; ++g)
#pragma unroll
    for (int t = 0; t < 2; ++t)
#pragma unroll
      for (int r = 0; r < 4; ++r) {
        int o = o0 + g * 16 + l4 * 4 + r;
        int n = t * 16 + l15;
        partial[((size_t)s * 1024 + o) * 32 + n] = acc[g][t][r];
      }
}

__global__ __launch_bounds__(256) void fc1_fin(const float* __restrict__ partial,
                                               const double* __restrict__ st,
                                               const float* __restrict__ fb,
                                               float* __restrict__ fc1T) {
  int i = blockIdx.x * 256 + threadIdx.x;  // 32768
  int o = i >> 5;
  float s = 0.f;
#pragma unroll 8
  for (int t = 0; t < 128; ++t) s += partial[(size_t)t * 32768 + i];
  float alpha = tern_alpha_d(st, 33554432.0);
  fc1T[i] = fmaxf(fmaf(s, alpha, fb[o]), 0.f);
}

// ---------------- FC2 (row-parallel; tiny) ----------------
__global__ __launch_bounds__(256) void fc2_kernel(const float* __restrict__ xT,
                                                  const int8_t* __restrict__ codes,
                                                  const double* __restrict__ st,
                                                  const float* __restrict__ fb,
                                                  float* __restrict__ out) {
  const int o = blockIdx.x;
  float acc[32];
#pragma unroll
  for (int j = 0; j < 32; ++j) acc[j] = 0.f;
  const int8_t* crow = codes + (size_t)o * 1024;
  for (int k = threadIdx.x; k < 1024; k += 256) {
    int cv = crow[k];
    if (cv != 0) {
      float c = (float)cv;
      const float4* pv = (const float4*)(xT + ((size_t)k << 5));
#pragma unroll
      for (int j = 0; j < 8; ++j) {
        float4 v = pv[j];
        acc[4 * j + 0] = fmaf(c, v.x, acc[4 * j + 0]);
        acc[4 * j + 1] = fmaf(c, v.y, acc[4 * j + 1]);
        acc[4 * j + 2] = fmaf(c, v.z, acc[4 * j + 2]);
        acc[4 * j + 3] = fmaf(c, v.w, acc[4 * j + 3]);
      }
    }
  }
#pragma unroll
  for (int j = 0; j < 32; ++j) {
#pragma unroll
    for (int off = 32; off > 0; off >>= 1) acc[j] += __shfl_down(acc[j], off);
  }
  __shared__ float red[4][32];
  int lane = threadIdx.x & 63, wv = threadIdx.x >> 6;
  if (lane == 0) {
#pragma unroll
    for (int j = 0; j < 32; ++j) red[wv][j] = acc[j];
  }
  __syncthreads();
  if (threadIdx.x < 32) {
    int n = threadIdx.x;
    float alpha = tern_alpha_d(st, 1024000.0);
    out[(size_t)n * 1000 + o] = (red[0][n] + red[1][n] + red[2][n] + red[3][n]) * alpha + fb[o];
  }
}

// ---------------- host ----------------
extern "C" void kernel_launch(void* const* d_in, const int* in_sizes, int n_in, void* d_out,
                              int out_size, void* d_ws, size_t ws_size, hipStream_t stream) {
  const float* x = (const float*)d_in[0];
  const float* w1 = (const float*)d_in[1];
  const float* g1 = (const float*)d_in[3];
  const float* be1 = (const float*)d_in[4];
  const float* w2 = (const float*)d_in[5];
  const float* g2 = (const float*)d_in[7];
  const float* be2 = (const float*)d_in[8];
  const float* w3 = (const float*)d_in[9];
  const float* g3 = (const float*)d_in[11];
  const float* be3 = (const float*)d_in[12];
  const float* w4 = (const float*)d_in[13];
  const float* g4 = (const float*)d_in[15];
  const float* be4 = (const float*)d_in[16];
  const float* fw1 = (const float*)d_in[17];
  const float* fb1 = (const float*)d_in[18];
  const float* fw2 = (const float*)d_in[19];
  const float* fb2 = (const float*)d_in[20];
  // b1..b4 cancel exactly under training-mode BN (alpha-folded finalize).
  (void)in_sizes; (void)n_in; (void)out_size; (void)ws_size;

  char* ws = (char*)d_ws;
  size_t off = 0;
  auto alloc = [&](size_t bytes) {
    size_t o = off;
    off += (bytes + 255) & ~(size_t)255;
    return o;
  };
  unsigned short* wb1 = (unsigned short*)(ws + alloc((size_t)2048 * 2));     // [64][32] im2col-27
  unsigned short* wb2 = (unsigned short*)(ws + alloc((size_t)73728 * 2));    // packed
  unsigned short* wb3 = (unsigned short*)(ws + alloc((size_t)294912 * 2));   // packed
  unsigned short* wb4 = (unsigned short*)(ws + alloc((size_t)1179648 * 2));  // packed
  int8_t* c1 = (int8_t*)(ws + alloc((size_t)33554432));  // fc1 int8 codes [1024][32768]
  int8_t* c2 = (int8_t*)(ws + alloc((size_t)1024000));
  double* dst = (double*)(ws + alloc((size_t)(32 + 3 * 384) * 8));
  double* absB = dst + 32;
  double* msB = absB + 384;
  double* cntB = msB + 384;
  float* scsh = (float*)(ws + alloc((size_t)4096 * 4));
  double* pS = (double*)(ws + alloc((size_t)262144 * 8));  // max: L1 4096p x 64c
  double* pQ = (double*)(ws + alloc((size_t)262144 * 8));
  float* bufY = (float*)(ws + alloc((size_t)16777216 * 4));  // 67MB: z / fc1part
  float* bufA = (float*)(ws + alloc((size_t)8388608 * 4));   // 33.5MB: pooled NHWC
  unsigned short* actHi = (unsigned short*)(ws + alloc((size_t)1048576 * 2));
  unsigned short* actLo = (unsigned short*)(ws + alloc((size_t)1048576 * 2));
  float* fc1T = (float*)(ws + alloc((size_t)32768 * 4));  // [1024][32]
  float* fc1part = bufY;  // [128][1024][32] = 16.8 MB; bufY dead by FC time

  hipMemsetAsync(dst, 0, (32 + 3 * 384) * 8, stream);

  // ternarize stats: flat proportional grid (exact-fit block ranges).
  TDescs ta;
  ta.d[0] = {fw1, 33554432, 0, 8192, 4};
  ta.d[1] = {w4, 1179648, 8192, 288, 3};
  ta.d[2] = {fw2, 1024000, 8480, 250, 5};
  ta.d[3] = {w3, 294912, 8730, 72, 2};
  ta.d[4] = {w2, 73728, 8802, 18, 1};
  ta.d[5] = {w1, 1728, 8820, 1, 0};
  tern_abs_all<<<8821, 256, 0, stream>>>(ta, absB);
  MDescs tm;
  tm.d[0] = {fw1, c1, 33554432, 0, 8192, 4};
  tm.d[1] = {w4, nullptr, 1179648, 8192, 288, 3};
  tm.d[2] = {fw2, c2, 1024000, 8480, 250, 5};
  tm.d[3] = {w3, nullptr, 294912, 8730, 72, 2};
  tm.d[4] = {w2, nullptr, 73728, 8802, 18, 1};
  tm.d[5] = {w1, nullptr, 1728, 8820, 1, 0};
  tern_masked_code_all<<<8821, 256, 0, stream>>>(tm, absB, msB, cntB);
  tern_collapse<<<6, 64, 0, stream>>>(absB, msB, cntB, dst);
  tern_write_convb_pad<<<8, 256, 0, stream>>>(w1, absB + 0 * 64, wb1);
  tern_write_convb<<<288, 256, 0, stream>>>(w2, absB + 1 * 64, 73728, 64, wb2);
  tern_write_convb<<<1152, 256, 0, stream>>>(w3, absB + 2 * 64, 294912, 128, wb3);
  tern_write_convb<<<4608, 256, 0, stream>>>(w4, absB + 3 * 64, 1179648, 256, wb4);

  float* ss1 = scsh;
  float* ss2 = scsh + 128;
  float* ss3 = scsh + 512;
  float* ss4 = scsh + 1024;

  // Layer 1 (im2col-27, reads x NCHW directly), two-pass recompute; pooled1 -> NHWC bufA.
  conv1_mfma_stats<<<dim3(128, 1, 32), 128, 0, stream>>>(x, wb1, pS, pQ);
  bn_fin_alpha<<<64, 256, 0, stream>>>(pS, pQ, 4096, g1, be1, 524288.0, dst + 0, 1728.0, ss1,
                                       64);
  conv1_mfma_pool<<<dim3(128, 1, 32), 128, 0, stream>>>(x, wb1, ss1, bufA);

  // Layer 2: 64->128 @64x64 (reads pooled1 NHWC in bufA; z -> bufY)
  conv_mfma<64, 64, 8><<<dim3(32, 1, 32), 256, 0, stream>>>(bufA, wb2, bufY, 128, pS, pQ);
  bn_fin_alpha<<<128, 256, 0, stream>>>(pS, pQ, 1024, g2, be2, 131072.0, dst + 4, 73728.0, ss2,
                                        128);
  bn_pool_nhwc<<<dim3(2, 16, 32), 256, 0, stream>>>(bufY, ss2, 128, 5, bufA);

  // Layer 3: 128->256 @32x32
  conv_mfma<128, 32, 4><<<dim3(16, 2, 32), 256, 0, stream>>>(bufA, wb3, bufY, 256, pS, pQ);
  bn_fin_alpha<<<256, 256, 0, stream>>>(pS, pQ, 512, g3, be3, 32768.0, dst + 8, 294912.0, ss3,
                                        256);
  bn_pool_nhwc<<<dim3(4, 4, 32), 256, 0, stream>>>(bufY, ss3, 256, 4, bufA);

  // Layer 4: 256->512 @16x16; fused BN+pool+hilo writes actHi/actLo directly
  conv_mfma<256, 16, 2><<<dim3(8, 4, 32), 256, 0, stream>>>(bufA, wb4, bufY, 512, pS, pQ);
  bn_fin_alpha<<<512, 256, 0, stream>>>(pS, pQ, 256, g4, be4, 8192.0, dst + 12, 1179648.0, ss4,
                                        512);
  bn_pool_hilo<<<4096, 256, 0, stream>>>(bufY, ss4, actHi, actLo);

  // FC1 (int8 codes -> in-register bf16), 1024 blocks; then finalize + FC2
  fc1_mfma<<<dim3(8, 128), 256, 0, stream>>>(c1, actHi, actLo, fc1part);
  fc1_fin<<<128, 256, 0, stream>>>(fc1part, dst + 16, fb1, fc1T);
  fc2_kernel<<<1000, 256, 0, stream>>>(fc1T, c2, dst + 20, fb2, (float*)d_out);
}